// Round 4
// baseline (952.356 us; speedup 1.0000x reference)
//
#include <hip/hip_runtime.h>
#include <hip/hip_fp16.h>
#include <math.h>

constexpr int F = 128;
constexpr int C = 40;
constexpr int SCAN_TILE = 1024;
constexpr int LDH = 136;  // padded LDS stride in halves
constexpr int BSHIFT = 8;            // 256 dst per bucket
constexpr int BSIZE = 1 << BSHIFT;

typedef __attribute__((ext_vector_type(8))) _Float16 half8;
typedef __attribute__((ext_vector_type(4))) float float4v;

// ---------------- CSR build ----------------

__global__ void hist_kernel(const int* __restrict__ dst, int E, int* __restrict__ count) {
    int i = blockIdx.x * blockDim.x + threadIdx.x;
    if (i < E) atomicAdd(&count[dst[i]], 1);
}

__global__ __launch_bounds__(256) void scan_reduce_kernel(const int* __restrict__ count, int N,
                                                          int* __restrict__ partials) {
    __shared__ int red[256];
    int t = threadIdx.x;
    int base = blockIdx.x * SCAN_TILE + t * 4;
    int s = 0;
    if (base + 3 < N) {
        int4 c = *((const int4*)(count + base));
        s = c.x + c.y + c.z + c.w;
    } else {
        for (int j = 0; j < 4; ++j) if (base + j < N) s += count[base + j];
    }
    red[t] = s;
    __syncthreads();
    for (int d = 128; d > 0; d >>= 1) {
        if (t < d) red[t] += red[t + d];
        __syncthreads();
    }
    if (t == 0) partials[blockIdx.x] = red[0];
}

__global__ __launch_bounds__(256) void scan_partials_kernel(int* __restrict__ partials, int B1,
                                                            int* __restrict__ partials_ex,
                                                            int* __restrict__ row_start, int N, int E) {
    __shared__ int tmp[256];
    int t = threadIdx.x;
    int v = (t < B1) ? partials[t] : 0;
    tmp[t] = v;
    __syncthreads();
    for (int d = 1; d < 256; d <<= 1) {
        int add = (t >= d) ? tmp[t - d] : 0;
        __syncthreads();
        tmp[t] += add;
        __syncthreads();
    }
    if (t < B1) partials_ex[t] = tmp[t] - v;
    if (t == 0) row_start[N] = E;
}

__global__ __launch_bounds__(256) void scan_write_kernel(const int* __restrict__ count, int N,
                                                         const int* __restrict__ partials_ex,
                                                         int* __restrict__ row_start) {
    __shared__ int tmp[256];
    int t = threadIdx.x;
    int base = blockIdx.x * SCAN_TILE + t * 4;
    int4 c = make_int4(0, 0, 0, 0);
    if (base + 3 < N) {
        c = *((const int4*)(count + base));
    } else {
        if (base + 0 < N) c.x = count[base + 0];
        if (base + 1 < N) c.y = count[base + 1];
        if (base + 2 < N) c.z = count[base + 2];
        if (base + 3 < N) c.w = count[base + 3];
    }
    int s = c.x + c.y + c.z + c.w;
    tmp[t] = s;
    __syncthreads();
    for (int d = 1; d < 256; d <<= 1) {
        int add = (t >= d) ? tmp[t - d] : 0;
        __syncthreads();
        tmp[t] += add;
        __syncthreads();
    }
    int off = tmp[t] - s + partials_ex[blockIdx.x];
    int e0 = off, e1 = off + c.x, e2 = e1 + c.y, e3 = e2 + c.z;
    if (base + 0 < N) row_start[base + 0] = e0;
    if (base + 1 < N) row_start[base + 1] = e1;
    if (base + 2 < N) row_start[base + 2] = e2;
    if (base + 3 < N) row_start[base + 3] = e3;
}

// bucket_pos[b] = row_start[b*BSIZE]
__global__ void bucket_init_kernel(const int* __restrict__ row_start, int N, int NB,
                                   int* __restrict__ bucket_pos) {
    int b = blockIdx.x * blockDim.x + threadIdx.x;
    if (b < NB) {
        int base = b << BSHIFT;
        bucket_pos[b] = row_start[base < N ? base : N];
    }
}

// phase A: route (src,dst) pairs to coarse buckets; writes cluster at ~NB moving tails
__global__ void bucket_scatter_a_kernel(const int* __restrict__ src, const int* __restrict__ dst,
                                        int E, int* __restrict__ bucket_pos,
                                        int2* __restrict__ pairs) {
    int i = blockIdx.x * blockDim.x + threadIdx.x;
    if (i < E) {
        int d = dst[i];
        int p = atomicAdd(&bucket_pos[d >> BSHIFT], 1);
        pairs[p] = make_int2(src[i], d);
    }
}

// phase B: one block per bucket; finish sort with LDS atomics; writes confined to ~16KB window
__global__ __launch_bounds__(256) void bucket_scatter_b_kernel(const int2* __restrict__ pairs,
                                                               const int* __restrict__ row_start,
                                                               int N, int* __restrict__ src_sorted) {
    __shared__ int pos[BSIZE];
    int b = blockIdx.x, t = threadIdx.x;
    int base = b << BSHIFT;
    int nloc = min(BSIZE, N - base);
    for (int i = t; i < nloc; i += 256) pos[i] = row_start[base + i];
    __syncthreads();
    int start = row_start[base];
    int end = row_start[(base + BSIZE <= N) ? base + BSIZE : N];
    for (int i = start + t; i < end; i += 256) {
        int2 e = pairs[i];
        int p = atomicAdd(&pos[e.y - base], 1);
        src_sorted[p] = e.x;
    }
}

// ---------------- prep: fp32 -> fp16 feature copy ----------------

__global__ void conv_f16_kernel(const float* __restrict__ in, __half* __restrict__ out, int n4) {
    int i = blockIdx.x * blockDim.x + threadIdx.x;
    if (i >= n4) return;
    float4 v = ((const float4*)in)[i];
    __half2 a = __floats2half2_rn(v.x, v.y);
    __half2 b = __floats2half2_rn(v.z, v.w);
    uint2 o;
    o.x = __builtin_bit_cast(unsigned, a);
    o.y = __builtin_bit_cast(unsigned, b);
    ((uint2*)out)[i] = o;
}

// ---------------- prep: weight transpose fp32 [K=128][Nin] -> fp16 [Npad][128] ----------------

__global__ __launch_bounds__(256) void prep_weights_kernel(
        const float* __restrict__ w1, const float* __restrict__ w2,
        const float* __restrict__ w3, const float* __restrict__ w4,
        __half* __restrict__ w1t, __half* __restrict__ w2t,
        __half* __restrict__ w3t, __half* __restrict__ w4t) {
    __shared__ float lds[128 * 128];
    const float* in; __half* outp; int Nin, Npad;
    switch (blockIdx.x) {
        case 0:  in = w1; outp = w1t; Nin = 128; Npad = 128; break;
        case 1:  in = w2; outp = w2t; Nin = 128; Npad = 128; break;
        case 2:  in = w3; outp = w3t; Nin = 128; Npad = 128; break;
        default: in = w4; outp = w4t; Nin = 40;  Npad = 48;  break;
    }
    int t = threadIdx.x;
    int nf4 = 128 * Nin / 4;
    for (int i = t; i < nf4; i += 256)
        ((float4*)lds)[i] = ((const float4*)in)[i];
    __syncthreads();
    int total = Npad * 64;  // half2 count
    for (int i = t; i < total; i += 256) {
        int n = i >> 6, k2 = (i & 63) * 2;
        float lo = 0.f, hi = 0.f;
        if (n < Nin) {
            lo = lds[k2 * Nin + n];
            hi = lds[(k2 + 1) * Nin + n];
        }
        __half2 h = __floats2half2_rn(lo, hi);
        ((unsigned*)outp)[i] = __builtin_bit_cast(unsigned, h);
    }
}

// ---------------- aggregation (fp16 feat, fp32 accumulate) ----------------

__global__ __launch_bounds__(256) void agg_f16_kernel(const __half* __restrict__ feat,
        const int* __restrict__ row_start, const int* __restrict__ src_sorted,
        const float* __restrict__ eps_ptr, __half* __restrict__ out, int N) {
    int wid = (int)((blockIdx.x * blockDim.x + threadIdx.x) >> 6);
    int lane = threadIdx.x & 63;
    if (wid >= N) return;
    int hf = lane >> 5, l32 = lane & 31;
    int s = row_start[wid], e = row_start[wid + 1];
    float a0 = 0.f, a1 = 0.f, a2 = 0.f, a3 = 0.f;
    float b0 = 0.f, b1 = 0.f, b2 = 0.f, b3 = 0.f;
    int i = s + hf;
    for (; i + 2 < e; i += 4) {
        int sv0 = src_sorted[i];
        int sv1 = src_sorted[i + 2];
        uint2 u0 = *(((const uint2*)(feat + (size_t)sv0 * F)) + l32);
        uint2 u1 = *(((const uint2*)(feat + (size_t)sv1 * F)) + l32);
        float2 f0 = __half22float2(__builtin_bit_cast(__half2, u0.x));
        float2 f1 = __half22float2(__builtin_bit_cast(__half2, u0.y));
        float2 f2 = __half22float2(__builtin_bit_cast(__half2, u1.x));
        float2 f3 = __half22float2(__builtin_bit_cast(__half2, u1.y));
        a0 += f0.x; a1 += f0.y; a2 += f1.x; a3 += f1.y;
        b0 += f2.x; b1 += f2.y; b2 += f3.x; b3 += f3.y;
    }
    if (i < e) {
        int sv = src_sorted[i];
        uint2 u = *(((const uint2*)(feat + (size_t)sv * F)) + l32);
        float2 f0 = __half22float2(__builtin_bit_cast(__half2, u.x));
        float2 f1 = __half22float2(__builtin_bit_cast(__half2, u.y));
        a0 += f0.x; a1 += f0.y; a2 += f1.x; a3 += f1.y;
    }
    a0 += b0; a1 += b1; a2 += b2; a3 += b3;
    a0 += __shfl_xor(a0, 32);
    a1 += __shfl_xor(a1, 32);
    a2 += __shfl_xor(a2, 32);
    a3 += __shfl_xor(a3, 32);
    if (hf == 0) {
        float ep1 = 1.0f + *eps_ptr;
        uint2 u = *(((const uint2*)(feat + (size_t)wid * F)) + l32);
        float2 s0 = __half22float2(__builtin_bit_cast(__half2, u.x));
        float2 s1 = __half22float2(__builtin_bit_cast(__half2, u.y));
        a0 = fmaf(ep1, s0.x, a0);
        a1 = fmaf(ep1, s0.y, a1);
        a2 = fmaf(ep1, s1.x, a2);
        a3 = fmaf(ep1, s1.y, a3);
        __half2 o0 = __floats2half2_rn(a0, a1);
        __half2 o1 = __floats2half2_rn(a2, a3);
        uint2 ou;
        ou.x = __builtin_bit_cast(unsigned, o0);
        ou.y = __builtin_bit_cast(unsigned, o1);
        *(((uint2*)(out + (size_t)wid * F)) + l32) = ou;
    }
}

// ---------------- mlp1 (MFMA): out = relu(relu(A@w1+b1)@w2+b2), fp16 in/out ----------------

__global__ __launch_bounds__(256) void mlp1_mfma_kernel(const __half* __restrict__ A,
        const __half* __restrict__ w1t, const float* __restrict__ b1,
        const __half* __restrict__ w2t, const float* __restrict__ b2,
        __half* __restrict__ out, int N) {
    __shared__ __half ldsA[64 * LDH];
    __shared__ __half ldsW[128 * LDH];
    __shared__ float ldsB[256];
    int t = threadIdx.x;
    int wave = t >> 6, lane = t & 63, quad = lane >> 4, l16 = lane & 15;
    int br = blockIdx.x * 64;
    if (t < 128) ldsB[t] = b1[t];
    else         ldsB[t] = b2[t - 128];
    for (int i = t; i < 1024; i += 256) {
        int r = i >> 4, c = i & 15;
        int gr = br + r;
        uint4 v = make_uint4(0u, 0u, 0u, 0u);
        if (gr < N) v = *((const uint4*)(A + (size_t)gr * F + c * 8));
        *((uint4*)&ldsA[r * LDH + c * 8]) = v;
    }
    for (int i = t; i < 2048; i += 256) {
        int r = i >> 4, c = i & 15;
        *((uint4*)&ldsW[r * LDH + c * 8]) = *((const uint4*)(w1t + r * 128 + c * 8));
    }
    __syncthreads();

    int ct0 = wave * 2;
    float4v acc[4][2];
    float4v zero = {0.f, 0.f, 0.f, 0.f};
#pragma unroll
    for (int i = 0; i < 4; ++i)
#pragma unroll
        for (int j = 0; j < 2; ++j) acc[i][j] = zero;

#pragma unroll
    for (int ks = 0; ks < 4; ++ks) {
        half8 af[4], wf[2];
#pragma unroll
        for (int i = 0; i < 4; ++i)
            af[i] = *((const half8*)&ldsA[(i * 16 + l16) * LDH + ks * 32 + quad * 8]);
#pragma unroll
        for (int j = 0; j < 2; ++j)
            wf[j] = *((const half8*)&ldsW[((ct0 + j) * 16 + l16) * LDH + ks * 32 + quad * 8]);
#pragma unroll
        for (int i = 0; i < 4; ++i)
#pragma unroll
            for (int j = 0; j < 2; ++j)
                acc[i][j] = __builtin_amdgcn_mfma_f32_16x16x32_f16(wf[j], af[i], acc[i][j], 0, 0, 0);
    }
    __syncthreads();
#pragma unroll
    for (int j = 0; j < 2; ++j) {
        int c = ct0 + j;
        float4 bb = *((const float4*)&ldsB[c * 16 + quad * 4]);
#pragma unroll
        for (int i = 0; i < 4; ++i) {
            float v0 = acc[i][j][0] + bb.x; v0 = v0 > 0.f ? v0 : 0.f;
            float v1 = acc[i][j][1] + bb.y; v1 = v1 > 0.f ? v1 : 0.f;
            float v2 = acc[i][j][2] + bb.z; v2 = v2 > 0.f ? v2 : 0.f;
            float v3 = acc[i][j][3] + bb.w; v3 = v3 > 0.f ? v3 : 0.f;
            __half2 h0 = __floats2half2_rn(v0, v1);
            __half2 h1 = __floats2half2_rn(v2, v3);
            uint2 o;
            o.x = __builtin_bit_cast(unsigned, h0);
            o.y = __builtin_bit_cast(unsigned, h1);
            *((uint2*)&ldsA[(i * 16 + l16) * LDH + c * 16 + quad * 4]) = o;
        }
    }
    for (int i = t; i < 2048; i += 256) {
        int r = i >> 4, c = i & 15;
        *((uint4*)&ldsW[r * LDH + c * 8]) = *((const uint4*)(w2t + r * 128 + c * 8));
    }
    __syncthreads();

#pragma unroll
    for (int i = 0; i < 4; ++i)
#pragma unroll
        for (int j = 0; j < 2; ++j) acc[i][j] = zero;
#pragma unroll
    for (int ks = 0; ks < 4; ++ks) {
        half8 af[4], wf[2];
#pragma unroll
        for (int i = 0; i < 4; ++i)
            af[i] = *((const half8*)&ldsA[(i * 16 + l16) * LDH + ks * 32 + quad * 8]);
#pragma unroll
        for (int j = 0; j < 2; ++j)
            wf[j] = *((const half8*)&ldsW[((ct0 + j) * 16 + l16) * LDH + ks * 32 + quad * 8]);
#pragma unroll
        for (int i = 0; i < 4; ++i)
#pragma unroll
            for (int j = 0; j < 2; ++j)
                acc[i][j] = __builtin_amdgcn_mfma_f32_16x16x32_f16(wf[j], af[i], acc[i][j], 0, 0, 0);
    }
    __syncthreads();
#pragma unroll
    for (int j = 0; j < 2; ++j) {
        int c = ct0 + j;
        float4 bb = *((const float4*)&ldsB[128 + c * 16 + quad * 4]);
#pragma unroll
        for (int i = 0; i < 4; ++i) {
            float v0 = acc[i][j][0] + bb.x; v0 = v0 > 0.f ? v0 : 0.f;
            float v1 = acc[i][j][1] + bb.y; v1 = v1 > 0.f ? v1 : 0.f;
            float v2 = acc[i][j][2] + bb.z; v2 = v2 > 0.f ? v2 : 0.f;
            float v3 = acc[i][j][3] + bb.w; v3 = v3 > 0.f ? v3 : 0.f;
            __half2 h0 = __floats2half2_rn(v0, v1);
            __half2 h1 = __floats2half2_rn(v2, v3);
            uint2 o;
            o.x = __builtin_bit_cast(unsigned, h0);
            o.y = __builtin_bit_cast(unsigned, h1);
            *((uint2*)&ldsA[(i * 16 + l16) * LDH + c * 16 + quad * 4]) = o;
        }
    }
    __syncthreads();
    for (int i = t; i < 1024; i += 256) {
        int r = i >> 4, c = i & 15;
        int gr = br + r;
        if (gr < N)
            *((uint4*)(out + (size_t)gr * F + c * 8)) = *((const uint4*)&ldsA[r * LDH + c * 8]);
    }
}

// ---------------- mlp2 (MFMA): out = log_softmax(relu(A@w3+b3)@w4+b4) ----------------

__global__ __launch_bounds__(256) void mlp2_mfma_kernel(const __half* __restrict__ A,
        const __half* __restrict__ w3t, const float* __restrict__ b3,
        const __half* __restrict__ w4t, const float* __restrict__ b4,
        float* __restrict__ out, int N) {
    __shared__ __half ldsA[64 * LDH];
    __shared__ __half ldsW[128 * LDH];
    __shared__ float ldsB[176];
    int t = threadIdx.x;
    int wave = t >> 6, lane = t & 63, quad = lane >> 4, l16 = lane & 15;
    int br = blockIdx.x * 64;
    if (t < 128) ldsB[t] = b3[t];
    else if (t < 176) ldsB[t] = (t - 128 < C) ? b4[t - 128] : 0.f;
    for (int i = t; i < 1024; i += 256) {
        int r = i >> 4, c = i & 15;
        int gr = br + r;
        uint4 v = make_uint4(0u, 0u, 0u, 0u);
        if (gr < N) v = *((const uint4*)(A + (size_t)gr * F + c * 8));
        *((uint4*)&ldsA[r * LDH + c * 8]) = v;
    }
    for (int i = t; i < 2048; i += 256) {
        int r = i >> 4, c = i & 15;
        *((uint4*)&ldsW[r * LDH + c * 8]) = *((const uint4*)(w3t + r * 128 + c * 8));
    }
    __syncthreads();

    int ct0 = wave * 2;
    float4v acc[4][2];
    float4v zero = {0.f, 0.f, 0.f, 0.f};
#pragma unroll
    for (int i = 0; i < 4; ++i)
#pragma unroll
        for (int j = 0; j < 2; ++j) acc[i][j] = zero;
#pragma unroll
    for (int ks = 0; ks < 4; ++ks) {
        half8 af[4], wf[2];
#pragma unroll
        for (int i = 0; i < 4; ++i)
            af[i] = *((const half8*)&ldsA[(i * 16 + l16) * LDH + ks * 32 + quad * 8]);
#pragma unroll
        for (int j = 0; j < 2; ++j)
            wf[j] = *((const half8*)&ldsW[((ct0 + j) * 16 + l16) * LDH + ks * 32 + quad * 8]);
#pragma unroll
        for (int i = 0; i < 4; ++i)
#pragma unroll
            for (int j = 0; j < 2; ++j)
                acc[i][j] = __builtin_amdgcn_mfma_f32_16x16x32_f16(wf[j], af[i], acc[i][j], 0, 0, 0);
    }
    __syncthreads();
#pragma unroll
    for (int j = 0; j < 2; ++j) {
        int c = ct0 + j;
        float4 bb = *((const float4*)&ldsB[c * 16 + quad * 4]);
#pragma unroll
        for (int i = 0; i < 4; ++i) {
            float v0 = acc[i][j][0] + bb.x; v0 = v0 > 0.f ? v0 : 0.f;
            float v1 = acc[i][j][1] + bb.y; v1 = v1 > 0.f ? v1 : 0.f;
            float v2 = acc[i][j][2] + bb.z; v2 = v2 > 0.f ? v2 : 0.f;
            float v3 = acc[i][j][3] + bb.w; v3 = v3 > 0.f ? v3 : 0.f;
            __half2 h0 = __floats2half2_rn(v0, v1);
            __half2 h1 = __floats2half2_rn(v2, v3);
            uint2 o;
            o.x = __builtin_bit_cast(unsigned, h0);
            o.y = __builtin_bit_cast(unsigned, h1);
            *((uint2*)&ldsA[(i * 16 + l16) * LDH + c * 16 + quad * 4]) = o;
        }
    }
    for (int i = t; i < 768; i += 256) {
        int r = i >> 4, c = i & 15;
        *((uint4*)&ldsW[r * LDH + c * 8]) = *((const uint4*)(w4t + r * 128 + c * 8));
    }
    __syncthreads();

    float4v acc4[3];
#pragma unroll
    for (int c = 0; c < 3; ++c) acc4[c] = zero;
#pragma unroll
    for (int ks = 0; ks < 4; ++ks) {
        half8 af = *((const half8*)&ldsA[(wave * 16 + l16) * LDH + ks * 32 + quad * 8]);
#pragma unroll
        for (int c = 0; c < 3; ++c) {
            half8 wf = *((const half8*)&ldsW[(c * 16 + l16) * LDH + ks * 32 + quad * 8]);
            acc4[c] = __builtin_amdgcn_mfma_f32_16x16x32_f16(wf, af, acc4[c], 0, 0, 0);
        }
    }
    float lv[3][4];
#pragma unroll
    for (int c = 0; c < 3; ++c) {
        float4 bb = *((const float4*)&ldsB[128 + c * 16 + quad * 4]);
        lv[c][0] = acc4[c][0] + bb.x;
        lv[c][1] = acc4[c][1] + bb.y;
        lv[c][2] = acc4[c][2] + bb.z;
        lv[c][3] = acc4[c][3] + bb.w;
    }
    bool tile2ok = (quad < 2);
    float m = -1e30f;
#pragma unroll
    for (int c = 0; c < 3; ++c) {
        if (c == 2 && !tile2ok) continue;
#pragma unroll
        for (int r = 0; r < 4; ++r) m = fmaxf(m, lv[c][r]);
    }
    m = fmaxf(m, __shfl_xor(m, 16));
    m = fmaxf(m, __shfl_xor(m, 32));
    float ssum = 0.f;
#pragma unroll
    for (int c = 0; c < 3; ++c) {
        if (c == 2 && !tile2ok) continue;
#pragma unroll
        for (int r = 0; r < 4; ++r) ssum += __expf(lv[c][r] - m);
    }
    ssum += __shfl_xor(ssum, 16);
    ssum += __shfl_xor(ssum, 32);
    float L = m + __logf(ssum);
    int node = br + wave * 16 + l16;
    if (node < N) {
#pragma unroll
        for (int c = 0; c < 3; ++c) {
            if (c == 2 && !tile2ok) continue;
            float4 o = make_float4(lv[c][0] - L, lv[c][1] - L, lv[c][2] - L, lv[c][3] - L);
            *((float4*)(out + (size_t)node * C + c * 16 + quad * 4)) = o;
        }
    }
}

// ---------------- launch ----------------

extern "C" void kernel_launch(void* const* d_in, const int* in_sizes, int n_in,
                              void* d_out, int out_size, void* d_ws, size_t ws_size,
                              hipStream_t stream) {
    const float* x    = (const float*)d_in[0];
    const int*   ei   = (const int*)d_in[1];
    const float* eps1 = (const float*)d_in[2];
    const float* w1   = (const float*)d_in[3];
    const float* b1   = (const float*)d_in[4];
    const float* w2   = (const float*)d_in[5];
    const float* b2   = (const float*)d_in[6];
    const float* eps2 = (const float*)d_in[7];
    const float* w3   = (const float*)d_in[8];
    const float* b3   = (const float*)d_in[9];
    const float* w4   = (const float*)d_in[10];
    const float* b4   = (const float*)d_in[11];
    float* out = (float*)d_out;

    int N = in_sizes[0] / F;       // 100000
    int E = in_sizes[1] / 2;       // 1600000
    const int* src = ei;
    const int* dst = ei + E;

    int B1 = (N + SCAN_TILE - 1) / SCAN_TILE;
    int NB = (N + BSIZE - 1) >> BSHIFT;   // coarse buckets

    // workspace layout
    __half* x_h  = (__half*)d_ws;                   // N*F
    __half* h0_h = x_h + (size_t)N * F;             // N*F
    __half* h_h  = h0_h + (size_t)N * F;            // N*F
    __half* w1t  = h_h + (size_t)N * F;             // 128*128
    __half* w2t  = w1t + 128 * 128;
    __half* w3t  = w2t + 128 * 128;
    __half* w4t  = w3t + 128 * 128;                 // 48*128
    int2* pairs      = (int2*)(w4t + 48 * 128);     // E int2 (8B-aligned by construction)
    int* count       = (int*)(pairs + E);           // N
    int* row_start   = count + N;                   // N+1
    int* src_sorted  = row_start + (N + 1);         // E
    int* bucket_pos  = src_sorted + E;              // NB
    int* partials    = bucket_pos + NB;             // 256
    int* partials_ex = partials + 256;              // 256

    // prep: fp16 conversions + weight transposes
    int n4 = N * F / 4;
    conv_f16_kernel<<<(n4 + 255) / 256, 256, 0, stream>>>(x, x_h, n4);
    prep_weights_kernel<<<4, 256, 0, stream>>>(w1, w2, w3, w4, w1t, w2t, w3t, w4t);

    // CSR build
    hipMemsetAsync(count, 0, (size_t)N * sizeof(int), stream);
    hist_kernel<<<(E + 255) / 256, 256, 0, stream>>>(dst, E, count);
    scan_reduce_kernel<<<B1, 256, 0, stream>>>(count, N, partials);
    scan_partials_kernel<<<1, 256, 0, stream>>>(partials, B1, partials_ex, row_start, N, E);
    scan_write_kernel<<<B1, 256, 0, stream>>>(count, N, partials_ex, row_start);
    bucket_init_kernel<<<(NB + 255) / 256, 256, 0, stream>>>(row_start, N, NB, bucket_pos);
    bucket_scatter_a_kernel<<<(E + 255) / 256, 256, 0, stream>>>(src, dst, E, bucket_pos, pairs);
    bucket_scatter_b_kernel<<<NB, 256, 0, stream>>>(pairs, row_start, N, src_sorted);

    // layer 1
    agg_f16_kernel<<<(N + 3) / 4, 256, 0, stream>>>(x_h, row_start, src_sorted, eps1, h0_h, N);
    mlp1_mfma_kernel<<<(N + 63) / 64, 256, 0, stream>>>(h0_h, w1t, b1, w2t, b2, h_h, N);
    // layer 2
    agg_f16_kernel<<<(N + 3) / 4, 256, 0, stream>>>(h_h, row_start, src_sorted, eps2, h0_h, N);
    mlp2_mfma_kernel<<<(N + 63) / 64, 256, 0, stream>>>(h0_h, w3t, b3, w4t, b4, out, N);
}

// Round 5
// 421.294 us; speedup vs baseline: 2.2605x; 2.2605x over previous
//
#include <hip/hip_runtime.h>
#include <hip/hip_fp16.h>
#include <math.h>

constexpr int F = 128;
constexpr int C = 40;
constexpr int SCAN_TILE = 1024;
constexpr int LDH = 136;   // padded LDS stride in halves
constexpr int BSHIFT = 8;  // 256 dst per coarse bucket
constexpr int BSIZE = 1 << BSHIFT;
constexpr int CHUNK = 8192;  // edges per phase-A block

typedef __attribute__((ext_vector_type(8))) _Float16 half8;
typedef __attribute__((ext_vector_type(4))) float float4v;

// ---------------- CSR build ----------------

__global__ void hist_kernel(const int* __restrict__ dst, int E, int* __restrict__ count) {
    int i = blockIdx.x * blockDim.x + threadIdx.x;
    if (i < E) atomicAdd(&count[dst[i]], 1);
}

__global__ __launch_bounds__(256) void scan_reduce_kernel(const int* __restrict__ count, int N,
                                                          int* __restrict__ partials) {
    __shared__ int red[256];
    int t = threadIdx.x;
    int base = blockIdx.x * SCAN_TILE + t * 4;
    int s = 0;
    if (base + 3 < N) {
        int4 c = *((const int4*)(count + base));
        s = c.x + c.y + c.z + c.w;
    } else {
        for (int j = 0; j < 4; ++j) if (base + j < N) s += count[base + j];
    }
    red[t] = s;
    __syncthreads();
    for (int d = 128; d > 0; d >>= 1) {
        if (t < d) red[t] += red[t + d];
        __syncthreads();
    }
    if (t == 0) partials[blockIdx.x] = red[0];
}

__global__ __launch_bounds__(256) void scan_partials_kernel(int* __restrict__ partials, int B1,
                                                            int* __restrict__ partials_ex,
                                                            int* __restrict__ row_start, int N, int E) {
    __shared__ int tmp[256];
    int t = threadIdx.x;
    int v = (t < B1) ? partials[t] : 0;
    tmp[t] = v;
    __syncthreads();
    for (int d = 1; d < 256; d <<= 1) {
        int add = (t >= d) ? tmp[t - d] : 0;
        __syncthreads();
        tmp[t] += add;
        __syncthreads();
    }
    if (t < B1) partials_ex[t] = tmp[t] - v;
    if (t == 0) row_start[N] = E;
}

__global__ __launch_bounds__(256) void scan_write_kernel(const int* __restrict__ count, int N,
                                                         const int* __restrict__ partials_ex,
                                                         int* __restrict__ row_start) {
    __shared__ int tmp[256];
    int t = threadIdx.x;
    int base = blockIdx.x * SCAN_TILE + t * 4;
    int4 c = make_int4(0, 0, 0, 0);
    if (base + 3 < N) {
        c = *((const int4*)(count + base));
    } else {
        if (base + 0 < N) c.x = count[base + 0];
        if (base + 1 < N) c.y = count[base + 1];
        if (base + 2 < N) c.z = count[base + 2];
        if (base + 3 < N) c.w = count[base + 3];
    }
    int s = c.x + c.y + c.z + c.w;
    tmp[t] = s;
    __syncthreads();
    for (int d = 1; d < 256; d <<= 1) {
        int add = (t >= d) ? tmp[t - d] : 0;
        __syncthreads();
        tmp[t] += add;
        __syncthreads();
    }
    int off = tmp[t] - s + partials_ex[blockIdx.x];
    int e0 = off, e1 = off + c.x, e2 = e1 + c.y, e3 = e2 + c.z;
    if (base + 0 < N) row_start[base + 0] = e0;
    if (base + 1 < N) row_start[base + 1] = e1;
    if (base + 2 < N) row_start[base + 2] = e2;
    if (base + 3 < N) row_start[base + 3] = e3;
}

// bucket_pos[b] = row_start[b*BSIZE]
__global__ void bucket_init_kernel(const int* __restrict__ row_start, int N, int NB,
                                   int* __restrict__ bucket_pos) {
    int b = blockIdx.x * blockDim.x + threadIdx.x;
    if (b < NB) {
        int base = b << BSHIFT;
        bucket_pos[b] = row_start[base < N ? base : N];
    }
}

// phase A: per-block LDS histogram -> one global atomic per (block,bucket) -> packed scatter.
// pack: (dst & 255) << 24 | src   (requires src < 2^24; here src < 2^17)
__global__ __launch_bounds__(256) void bucket_scatter_a_kernel(
        const int* __restrict__ src, const int* __restrict__ dst, int E, int NB,
        int* __restrict__ bucket_pos, unsigned* __restrict__ pairs) {
    __shared__ int hist[512];
    __shared__ int base[512];
    int t = threadIdx.x;
    int c0 = blockIdx.x * CHUNK;
    int cend = min(c0 + CHUNK, E);
    for (int i = t; i < NB; i += 256) hist[i] = 0;
    __syncthreads();
    for (int i = c0 + t; i < cend; i += 256)
        atomicAdd(&hist[dst[i] >> BSHIFT], 1);
    __syncthreads();
    for (int i = t; i < NB; i += 256) {
        int h = hist[i];
        base[i] = (h > 0) ? atomicAdd(&bucket_pos[i], h) : 0;
        hist[i] = 0;  // reuse as local offset
    }
    __syncthreads();
    for (int i = c0 + t; i < cend; i += 256) {
        int d = dst[i];
        int b = d >> BSHIFT;
        int p = base[b] + atomicAdd(&hist[b], 1);
        pairs[p] = ((unsigned)(d & (BSIZE - 1)) << 24) | (unsigned)src[i];
    }
}

// phase B: one block per bucket; finish sort with LDS atomics; writes within ~16KB window
__global__ __launch_bounds__(256) void bucket_scatter_b_kernel(const unsigned* __restrict__ pairs,
                                                               const int* __restrict__ row_start,
                                                               int N, int* __restrict__ src_sorted) {
    __shared__ int pos[BSIZE];
    int b = blockIdx.x, t = threadIdx.x;
    int base = b << BSHIFT;
    int nloc = min(BSIZE, N - base);
    for (int i = t; i < nloc; i += 256) pos[i] = row_start[base + i];
    __syncthreads();
    int start = row_start[base];
    int end = row_start[(base + BSIZE <= N) ? base + BSIZE : N];
    for (int i = start + t; i < end; i += 256) {
        unsigned u = pairs[i];
        int p = atomicAdd(&pos[u >> 24], 1);
        src_sorted[p] = (int)(u & 0xFFFFFFu >> 8);  // placeholder, fixed below
    }
}

// NOTE: the line above would be wrong; real kernel defined here instead.
__global__ __launch_bounds__(256) void bucket_scatter_b2_kernel(const unsigned* __restrict__ pairs,
                                                                const int* __restrict__ row_start,
                                                                int N, int* __restrict__ src_sorted) {
    __shared__ int pos[BSIZE];
    int b = blockIdx.x, t = threadIdx.x;
    int base = b << BSHIFT;
    int nloc = min(BSIZE, N - base);
    for (int i = t; i < nloc; i += 256) pos[i] = row_start[base + i];
    __syncthreads();
    int start = row_start[base];
    int end = row_start[(base + BSIZE <= N) ? base + BSIZE : N];
    for (int i = start + t; i < end; i += 256) {
        unsigned u = pairs[i];
        int p = atomicAdd(&pos[u >> 24], 1);
        src_sorted[p] = (int)(u & 0x00FFFFFFu);
    }
}

// ---------------- prep: fp32 -> fp16 feature copy ----------------

__global__ void conv_f16_kernel(const float* __restrict__ in, __half* __restrict__ out, int n4) {
    int i = blockIdx.x * blockDim.x + threadIdx.x;
    if (i >= n4) return;
    float4 v = ((const float4*)in)[i];
    __half2 a = __floats2half2_rn(v.x, v.y);
    __half2 b = __floats2half2_rn(v.z, v.w);
    uint2 o;
    o.x = __builtin_bit_cast(unsigned, a);
    o.y = __builtin_bit_cast(unsigned, b);
    ((uint2*)out)[i] = o;
}

// ---------------- prep: weight transpose fp32 [K=128][Nin] -> fp16 [Npad][128] ----------------

__global__ __launch_bounds__(256) void prep_weights_kernel(
        const float* __restrict__ w1, const float* __restrict__ w2,
        const float* __restrict__ w3, const float* __restrict__ w4,
        __half* __restrict__ w1t, __half* __restrict__ w2t,
        __half* __restrict__ w3t, __half* __restrict__ w4t) {
    __shared__ float lds[128 * 128];
    const float* in; __half* outp; int Nin, Npad;
    switch (blockIdx.x) {
        case 0:  in = w1; outp = w1t; Nin = 128; Npad = 128; break;
        case 1:  in = w2; outp = w2t; Nin = 128; Npad = 128; break;
        case 2:  in = w3; outp = w3t; Nin = 128; Npad = 128; break;
        default: in = w4; outp = w4t; Nin = 40;  Npad = 48;  break;
    }
    int t = threadIdx.x;
    int nf4 = 128 * Nin / 4;
    for (int i = t; i < nf4; i += 256)
        ((float4*)lds)[i] = ((const float4*)in)[i];
    __syncthreads();
    int total = Npad * 64;
    for (int i = t; i < total; i += 256) {
        int n = i >> 6, k2 = (i & 63) * 2;
        float lo = 0.f, hi = 0.f;
        if (n < Nin) {
            lo = lds[k2 * Nin + n];
            hi = lds[(k2 + 1) * Nin + n];
        }
        __half2 h = __floats2half2_rn(lo, hi);
        ((unsigned*)outp)[i] = __builtin_bit_cast(unsigned, h);
    }
}

// ---------------- aggregation (fp16 feat, fp32 accumulate) ----------------
// one wave per node; 4 quarter-waves, each covers the full 128-feat row (uint4 = 8 halves/lane
// over 16 lanes = 256B) and processes every 4th edge; 2x unroll -> 8 gathers in flight.

__global__ __launch_bounds__(256) void agg_f16_kernel(const __half* __restrict__ feat,
        const int* __restrict__ row_start, const int* __restrict__ src_sorted,
        const float* __restrict__ eps_ptr, __half* __restrict__ out, int N) {
    int wid = (int)((blockIdx.x * blockDim.x + threadIdx.x) >> 6);
    int lane = threadIdx.x & 63;
    if (wid >= N) return;
    int q = lane >> 4, l16 = lane & 15;
    int s = row_start[wid], e = row_start[wid + 1];
    float a[8] = {0.f, 0.f, 0.f, 0.f, 0.f, 0.f, 0.f, 0.f};
    float b[8] = {0.f, 0.f, 0.f, 0.f, 0.f, 0.f, 0.f, 0.f};
    int i = s + q;
    for (; i + 4 < e; i += 8) {
        int sv0 = src_sorted[i];
        int sv1 = src_sorted[i + 4];
        uint4 u0 = *(((const uint4*)(feat + (size_t)sv0 * F)) + l16);
        uint4 u1 = *(((const uint4*)(feat + (size_t)sv1 * F)) + l16);
        float2 f0 = __half22float2(__builtin_bit_cast(__half2, u0.x));
        float2 f1 = __half22float2(__builtin_bit_cast(__half2, u0.y));
        float2 f2 = __half22float2(__builtin_bit_cast(__half2, u0.z));
        float2 f3 = __half22float2(__builtin_bit_cast(__half2, u0.w));
        a[0] += f0.x; a[1] += f0.y; a[2] += f1.x; a[3] += f1.y;
        a[4] += f2.x; a[5] += f2.y; a[6] += f3.x; a[7] += f3.y;
        float2 g0 = __half22float2(__builtin_bit_cast(__half2, u1.x));
        float2 g1 = __half22float2(__builtin_bit_cast(__half2, u1.y));
        float2 g2 = __half22float2(__builtin_bit_cast(__half2, u1.z));
        float2 g3 = __half22float2(__builtin_bit_cast(__half2, u1.w));
        b[0] += g0.x; b[1] += g0.y; b[2] += g1.x; b[3] += g1.y;
        b[4] += g2.x; b[5] += g2.y; b[6] += g3.x; b[7] += g3.y;
    }
    if (i < e) {
        int sv = src_sorted[i];
        uint4 u = *(((const uint4*)(feat + (size_t)sv * F)) + l16);
        float2 f0 = __half22float2(__builtin_bit_cast(__half2, u.x));
        float2 f1 = __half22float2(__builtin_bit_cast(__half2, u.y));
        float2 f2 = __half22float2(__builtin_bit_cast(__half2, u.z));
        float2 f3 = __half22float2(__builtin_bit_cast(__half2, u.w));
        a[0] += f0.x; a[1] += f0.y; a[2] += f1.x; a[3] += f1.y;
        a[4] += f2.x; a[5] += f2.y; a[6] += f3.x; a[7] += f3.y;
    }
#pragma unroll
    for (int j = 0; j < 8; ++j) {
        a[j] += b[j];
        a[j] += __shfl_xor(a[j], 16);
        a[j] += __shfl_xor(a[j], 32);
    }
    if (q == 0) {
        float ep1 = 1.0f + *eps_ptr;
        uint4 u = *(((const uint4*)(feat + (size_t)wid * F)) + l16);
        float2 s0 = __half22float2(__builtin_bit_cast(__half2, u.x));
        float2 s1 = __half22float2(__builtin_bit_cast(__half2, u.y));
        float2 s2 = __half22float2(__builtin_bit_cast(__half2, u.z));
        float2 s3 = __half22float2(__builtin_bit_cast(__half2, u.w));
        a[0] = fmaf(ep1, s0.x, a[0]); a[1] = fmaf(ep1, s0.y, a[1]);
        a[2] = fmaf(ep1, s1.x, a[2]); a[3] = fmaf(ep1, s1.y, a[3]);
        a[4] = fmaf(ep1, s2.x, a[4]); a[5] = fmaf(ep1, s2.y, a[5]);
        a[6] = fmaf(ep1, s3.x, a[6]); a[7] = fmaf(ep1, s3.y, a[7]);
        uint4 ou;
        ou.x = __builtin_bit_cast(unsigned, __floats2half2_rn(a[0], a[1]));
        ou.y = __builtin_bit_cast(unsigned, __floats2half2_rn(a[2], a[3]));
        ou.z = __builtin_bit_cast(unsigned, __floats2half2_rn(a[4], a[5]));
        ou.w = __builtin_bit_cast(unsigned, __floats2half2_rn(a[6], a[7]));
        *(((uint4*)(out + (size_t)wid * F)) + l16) = ou;
    }
}

// ---------------- mlp1 (MFMA): out = relu(relu(A@w1+b1)@w2+b2), fp16 in/out ----------------

__global__ __launch_bounds__(256) void mlp1_mfma_kernel(const __half* __restrict__ A,
        const __half* __restrict__ w1t, const float* __restrict__ b1,
        const __half* __restrict__ w2t, const float* __restrict__ b2,
        __half* __restrict__ out, int N) {
    __shared__ __half ldsA[64 * LDH];
    __shared__ __half ldsW[128 * LDH];
    __shared__ float ldsB[256];
    int t = threadIdx.x;
    int wave = t >> 6, lane = t & 63, quad = lane >> 4, l16 = lane & 15;
    int br = blockIdx.x * 64;
    if (t < 128) ldsB[t] = b1[t];
    else         ldsB[t] = b2[t - 128];
    for (int i = t; i < 1024; i += 256) {
        int r = i >> 4, c = i & 15;
        int gr = br + r;
        uint4 v = make_uint4(0u, 0u, 0u, 0u);
        if (gr < N) v = *((const uint4*)(A + (size_t)gr * F + c * 8));
        *((uint4*)&ldsA[r * LDH + c * 8]) = v;
    }
    for (int i = t; i < 2048; i += 256) {
        int r = i >> 4, c = i & 15;
        *((uint4*)&ldsW[r * LDH + c * 8]) = *((const uint4*)(w1t + r * 128 + c * 8));
    }
    __syncthreads();

    int ct0 = wave * 2;
    float4v acc[4][2];
    float4v zero = {0.f, 0.f, 0.f, 0.f};
#pragma unroll
    for (int i = 0; i < 4; ++i)
#pragma unroll
        for (int j = 0; j < 2; ++j) acc[i][j] = zero;

#pragma unroll
    for (int ks = 0; ks < 4; ++ks) {
        half8 af[4], wf[2];
#pragma unroll
        for (int i = 0; i < 4; ++i)
            af[i] = *((const half8*)&ldsA[(i * 16 + l16) * LDH + ks * 32 + quad * 8]);
#pragma unroll
        for (int j = 0; j < 2; ++j)
            wf[j] = *((const half8*)&ldsW[((ct0 + j) * 16 + l16) * LDH + ks * 32 + quad * 8]);
#pragma unroll
        for (int i = 0; i < 4; ++i)
#pragma unroll
            for (int j = 0; j < 2; ++j)
                acc[i][j] = __builtin_amdgcn_mfma_f32_16x16x32_f16(wf[j], af[i], acc[i][j], 0, 0, 0);
    }
    __syncthreads();
#pragma unroll
    for (int j = 0; j < 2; ++j) {
        int c = ct0 + j;
        float4 bb = *((const float4*)&ldsB[c * 16 + quad * 4]);
#pragma unroll
        for (int i = 0; i < 4; ++i) {
            float v0 = acc[i][j][0] + bb.x; v0 = v0 > 0.f ? v0 : 0.f;
            float v1 = acc[i][j][1] + bb.y; v1 = v1 > 0.f ? v1 : 0.f;
            float v2 = acc[i][j][2] + bb.z; v2 = v2 > 0.f ? v2 : 0.f;
            float v3 = acc[i][j][3] + bb.w; v3 = v3 > 0.f ? v3 : 0.f;
            __half2 h0 = __floats2half2_rn(v0, v1);
            __half2 h1 = __floats2half2_rn(v2, v3);
            uint2 o;
            o.x = __builtin_bit_cast(unsigned, h0);
            o.y = __builtin_bit_cast(unsigned, h1);
            *((uint2*)&ldsA[(i * 16 + l16) * LDH + c * 16 + quad * 4]) = o;
        }
    }
    for (int i = t; i < 2048; i += 256) {
        int r = i >> 4, c = i & 15;
        *((uint4*)&ldsW[r * LDH + c * 8]) = *((const uint4*)(w2t + r * 128 + c * 8));
    }
    __syncthreads();

#pragma unroll
    for (int i = 0; i < 4; ++i)
#pragma unroll
        for (int j = 0; j < 2; ++j) acc[i][j] = zero;
#pragma unroll
    for (int ks = 0; ks < 4; ++ks) {
        half8 af[4], wf[2];
#pragma unroll
        for (int i = 0; i < 4; ++i)
            af[i] = *((const half8*)&ldsA[(i * 16 + l16) * LDH + ks * 32 + quad * 8]);
#pragma unroll
        for (int j = 0; j < 2; ++j)
            wf[j] = *((const half8*)&ldsW[((ct0 + j) * 16 + l16) * LDH + ks * 32 + quad * 8]);
#pragma unroll
        for (int i = 0; i < 4; ++i)
#pragma unroll
            for (int j = 0; j < 2; ++j)
                acc[i][j] = __builtin_amdgcn_mfma_f32_16x16x32_f16(wf[j], af[i], acc[i][j], 0, 0, 0);
    }
    __syncthreads();
#pragma unroll
    for (int j = 0; j < 2; ++j) {
        int c = ct0 + j;
        float4 bb = *((const float4*)&ldsB[128 + c * 16 + quad * 4]);
#pragma unroll
        for (int i = 0; i < 4; ++i) {
            float v0 = acc[i][j][0] + bb.x; v0 = v0 > 0.f ? v0 : 0.f;
            float v1 = acc[i][j][1] + bb.y; v1 = v1 > 0.f ? v1 : 0.f;
            float v2 = acc[i][j][2] + bb.z; v2 = v2 > 0.f ? v2 : 0.f;
            float v3 = acc[i][j][3] + bb.w; v3 = v3 > 0.f ? v3 : 0.f;
            __half2 h0 = __floats2half2_rn(v0, v1);
            __half2 h1 = __floats2half2_rn(v2, v3);
            uint2 o;
            o.x = __builtin_bit_cast(unsigned, h0);
            o.y = __builtin_bit_cast(unsigned, h1);
            *((uint2*)&ldsA[(i * 16 + l16) * LDH + c * 16 + quad * 4]) = o;
        }
    }
    __syncthreads();
    for (int i = t; i < 1024; i += 256) {
        int r = i >> 4, c = i & 15;
        int gr = br + r;
        if (gr < N)
            *((uint4*)(out + (size_t)gr * F + c * 8)) = *((const uint4*)&ldsA[r * LDH + c * 8]);
    }
}

// ---------------- mlp2 (MFMA): out = log_softmax(relu(A@w3+b3)@w4+b4) ----------------

__global__ __launch_bounds__(256) void mlp2_mfma_kernel(const __half* __restrict__ A,
        const __half* __restrict__ w3t, const float* __restrict__ b3,
        const __half* __restrict__ w4t, const float* __restrict__ b4,
        float* __restrict__ out, int N) {
    __shared__ __half ldsA[64 * LDH];
    __shared__ __half ldsW[128 * LDH];
    __shared__ float ldsB[176];
    int t = threadIdx.x;
    int wave = t >> 6, lane = t & 63, quad = lane >> 4, l16 = lane & 15;
    int br = blockIdx.x * 64;
    if (t < 128) ldsB[t] = b3[t];
    else if (t < 176) ldsB[t] = (t - 128 < C) ? b4[t - 128] : 0.f;
    for (int i = t; i < 1024; i += 256) {
        int r = i >> 4, c = i & 15;
        int gr = br + r;
        uint4 v = make_uint4(0u, 0u, 0u, 0u);
        if (gr < N) v = *((const uint4*)(A + (size_t)gr * F + c * 8));
        *((uint4*)&ldsA[r * LDH + c * 8]) = v;
    }
    for (int i = t; i < 2048; i += 256) {
        int r = i >> 4, c = i & 15;
        *((uint4*)&ldsW[r * LDH + c * 8]) = *((const uint4*)(w3t + r * 128 + c * 8));
    }
    __syncthreads();

    int ct0 = wave * 2;
    float4v acc[4][2];
    float4v zero = {0.f, 0.f, 0.f, 0.f};
#pragma unroll
    for (int i = 0; i < 4; ++i)
#pragma unroll
        for (int j = 0; j < 2; ++j) acc[i][j] = zero;
#pragma unroll
    for (int ks = 0; ks < 4; ++ks) {
        half8 af[4], wf[2];
#pragma unroll
        for (int i = 0; i < 4; ++i)
            af[i] = *((const half8*)&ldsA[(i * 16 + l16) * LDH + ks * 32 + quad * 8]);
#pragma unroll
        for (int j = 0; j < 2; ++j)
            wf[j] = *((const half8*)&ldsW[((ct0 + j) * 16 + l16) * LDH + ks * 32 + quad * 8]);
#pragma unroll
        for (int i = 0; i < 4; ++i)
#pragma unroll
            for (int j = 0; j < 2; ++j)
                acc[i][j] = __builtin_amdgcn_mfma_f32_16x16x32_f16(wf[j], af[i], acc[i][j], 0, 0, 0);
    }
    __syncthreads();
#pragma unroll
    for (int j = 0; j < 2; ++j) {
        int c = ct0 + j;
        float4 bb = *((const float4*)&ldsB[c * 16 + quad * 4]);
#pragma unroll
        for (int i = 0; i < 4; ++i) {
            float v0 = acc[i][j][0] + bb.x; v0 = v0 > 0.f ? v0 : 0.f;
            float v1 = acc[i][j][1] + bb.y; v1 = v1 > 0.f ? v1 : 0.f;
            float v2 = acc[i][j][2] + bb.z; v2 = v2 > 0.f ? v2 : 0.f;
            float v3 = acc[i][j][3] + bb.w; v3 = v3 > 0.f ? v3 : 0.f;
            __half2 h0 = __floats2half2_rn(v0, v1);
            __half2 h1 = __floats2half2_rn(v2, v3);
            uint2 o;
            o.x = __builtin_bit_cast(unsigned, h0);
            o.y = __builtin_bit_cast(unsigned, h1);
            *((uint2*)&ldsA[(i * 16 + l16) * LDH + c * 16 + quad * 4]) = o;
        }
    }
    for (int i = t; i < 768; i += 256) {
        int r = i >> 4, c = i & 15;
        *((uint4*)&ldsW[r * LDH + c * 8]) = *((const uint4*)(w4t + r * 128 + c * 8));
    }
    __syncthreads();

    float4v acc4[3];
#pragma unroll
    for (int c = 0; c < 3; ++c) acc4[c] = zero;
#pragma unroll
    for (int ks = 0; ks < 4; ++ks) {
        half8 af = *((const half8*)&ldsA[(wave * 16 + l16) * LDH + ks * 32 + quad * 8]);
#pragma unroll
        for (int c = 0; c < 3; ++c) {
            half8 wf = *((const half8*)&ldsW[(c * 16 + l16) * LDH + ks * 32 + quad * 8]);
            acc4[c] = __builtin_amdgcn_mfma_f32_16x16x32_f16(wf, af, acc4[c], 0, 0, 0);
        }
    }
    float lv[3][4];
#pragma unroll
    for (int c = 0; c < 3; ++c) {
        float4 bb = *((const float4*)&ldsB[128 + c * 16 + quad * 4]);
        lv[c][0] = acc4[c][0] + bb.x;
        lv[c][1] = acc4[c][1] + bb.y;
        lv[c][2] = acc4[c][2] + bb.z;
        lv[c][3] = acc4[c][3] + bb.w;
    }
    bool tile2ok = (quad < 2);
    float m = -1e30f;
#pragma unroll
    for (int c = 0; c < 3; ++c) {
        if (c == 2 && !tile2ok) continue;
#pragma unroll
        for (int r = 0; r < 4; ++r) m = fmaxf(m, lv[c][r]);
    }
    m = fmaxf(m, __shfl_xor(m, 16));
    m = fmaxf(m, __shfl_xor(m, 32));
    float ssum = 0.f;
#pragma unroll
    for (int c = 0; c < 3; ++c) {
        if (c == 2 && !tile2ok) continue;
#pragma unroll
        for (int r = 0; r < 4; ++r) ssum += __expf(lv[c][r] - m);
    }
    ssum += __shfl_xor(ssum, 16);
    ssum += __shfl_xor(ssum, 32);
    float L = m + __logf(ssum);
    int node = br + wave * 16 + l16;
    if (node < N) {
#pragma unroll
        for (int c = 0; c < 3; ++c) {
            if (c == 2 && !tile2ok) continue;
            float4 o = make_float4(lv[c][0] - L, lv[c][1] - L, lv[c][2] - L, lv[c][3] - L);
            *((float4*)(out + (size_t)node * C + c * 16 + quad * 4)) = o;
        }
    }
}

// ---------------- launch ----------------

extern "C" void kernel_launch(void* const* d_in, const int* in_sizes, int n_in,
                              void* d_out, int out_size, void* d_ws, size_t ws_size,
                              hipStream_t stream) {
    const float* x    = (const float*)d_in[0];
    const int*   ei   = (const int*)d_in[1];
    const float* eps1 = (const float*)d_in[2];
    const float* w1   = (const float*)d_in[3];
    const float* b1   = (const float*)d_in[4];
    const float* w2   = (const float*)d_in[5];
    const float* b2   = (const float*)d_in[6];
    const float* eps2 = (const float*)d_in[7];
    const float* w3   = (const float*)d_in[8];
    const float* b3   = (const float*)d_in[9];
    const float* w4   = (const float*)d_in[10];
    const float* b4   = (const float*)d_in[11];
    float* out = (float*)d_out;

    int N = in_sizes[0] / F;       // 100000
    int E = in_sizes[1] / 2;       // 1600000
    const int* src = ei;
    const int* dst = ei + E;

    int B1 = (N + SCAN_TILE - 1) / SCAN_TILE;
    int NB = (N + BSIZE - 1) >> BSHIFT;   // 391 coarse buckets (<= 512)
    int BA = (E + CHUNK - 1) / CHUNK;     // phase-A blocks

    // workspace layout
    __half* x_h  = (__half*)d_ws;                   // N*F
    __half* h0_h = x_h + (size_t)N * F;             // N*F
    __half* h_h  = h0_h + (size_t)N * F;            // N*F
    __half* w1t  = h_h + (size_t)N * F;             // 128*128
    __half* w2t  = w1t + 128 * 128;
    __half* w3t  = w2t + 128 * 128;
    __half* w4t  = w3t + 128 * 128;                 // 48*128
    unsigned* pairs  = (unsigned*)(w4t + 48 * 128); // E
    int* count       = (int*)(pairs + E);           // N
    int* row_start   = count + N;                   // N+1
    int* src_sorted  = row_start + (N + 1);         // E
    int* bucket_pos  = src_sorted + E;              // NB
    int* partials    = bucket_pos + 512;            // 256
    int* partials_ex = partials + 256;              // 256

    // prep: fp16 conversions + weight transposes
    int n4 = N * F / 4;
    conv_f16_kernel<<<(n4 + 255) / 256, 256, 0, stream>>>(x, x_h, n4);
    prep_weights_kernel<<<4, 256, 0, stream>>>(w1, w2, w3, w4, w1t, w2t, w3t, w4t);

    // CSR build
    hipMemsetAsync(count, 0, (size_t)N * sizeof(int), stream);
    hist_kernel<<<(E + 255) / 256, 256, 0, stream>>>(dst, E, count);
    scan_reduce_kernel<<<B1, 256, 0, stream>>>(count, N, partials);
    scan_partials_kernel<<<1, 256, 0, stream>>>(partials, B1, partials_ex, row_start, N, E);
    scan_write_kernel<<<B1, 256, 0, stream>>>(count, N, partials_ex, row_start);
    bucket_init_kernel<<<(NB + 255) / 256, 256, 0, stream>>>(row_start, N, NB, bucket_pos);
    bucket_scatter_a_kernel<<<BA, 256, 0, stream>>>(src, dst, E, NB, bucket_pos, pairs);
    bucket_scatter_b2_kernel<<<NB, 256, 0, stream>>>(pairs, row_start, N, src_sorted);

    // layer 1
    agg_f16_kernel<<<(N + 3) / 4, 256, 0, stream>>>(x_h, row_start, src_sorted, eps1, h0_h, N);
    mlp1_mfma_kernel<<<(N + 63) / 64, 256, 0, stream>>>(h0_h, w1t, b1, w2t, b2, h_h, N);
    // layer 2
    agg_f16_kernel<<<(N + 3) / 4, 256, 0, stream>>>(h_h, row_start, src_sorted, eps2, h0_h, N);
    mlp2_mfma_kernel<<<(N + 63) / 64, 256, 0, stream>>>(h0_h, w3t, b3, w4t, b4, out, N);
}

// Round 6
// 360.173 us; speedup vs baseline: 2.6442x; 1.1697x over previous
//
#include <hip/hip_runtime.h>
#include <hip/hip_fp16.h>
#include <math.h>

constexpr int F = 128;
constexpr int C = 40;
constexpr int LDH = 136;   // padded LDS stride in halves
constexpr int BSHIFT = 8;  // 256 dst per coarse bucket
constexpr int BSIZE = 1 << BSHIFT;
constexpr int CHUNK = 8192;  // edges per histogram/scatter block

typedef __attribute__((ext_vector_type(8))) _Float16 half8;
typedef __attribute__((ext_vector_type(4))) float float4v;

// ---------------- CSR build (coarse-bucket pipeline, no global fine histogram) ----------------

// coarse histogram: per-block LDS hist over NB buckets -> one global atomic per (block,bucket)
__global__ __launch_bounds__(256) void coarse_hist_kernel(const int* __restrict__ dst, int E, int NB,
                                                          int* __restrict__ coarse_count) {
    __shared__ int hist[512];
    int t = threadIdx.x;
    int c0 = blockIdx.x * CHUNK;
    int cend = min(c0 + CHUNK, E);
    for (int i = t; i < NB; i += 256) hist[i] = 0;
    __syncthreads();
    for (int i = c0 + t; i < cend; i += 256)
        atomicAdd(&hist[dst[i] >> BSHIFT], 1);
    __syncthreads();
    for (int i = t; i < NB; i += 256)
        if (hist[i]) atomicAdd(&coarse_count[i], hist[i]);
}

// single-block exclusive scan of NB (<=512) bucket counts
__global__ __launch_bounds__(512) void coarse_scan_kernel(const int* __restrict__ coarse_count,
                                                          int NB, int E,
                                                          int* __restrict__ coarse_start,
                                                          int* __restrict__ bucket_pos,
                                                          int* __restrict__ row_start, int N) {
    __shared__ int tmp[512];
    int t = threadIdx.x;
    int v = (t < NB) ? coarse_count[t] : 0;
    tmp[t] = v;
    __syncthreads();
    for (int d = 1; d < 512; d <<= 1) {
        int add = (t >= d) ? tmp[t - d] : 0;
        __syncthreads();
        tmp[t] += add;
        __syncthreads();
    }
    if (t < NB) {
        int ex = tmp[t] - v;
        coarse_start[t] = ex;
        bucket_pos[t] = ex;
    }
    if (t == 0) {
        coarse_start[NB] = E;
        row_start[N] = E;
    }
}

// phase A: per-block LDS histogram -> one global atomic per (block,bucket) -> packed scatter.
// pack: (dst & 255) << 24 | src   (src < 2^17 here)
__global__ __launch_bounds__(256) void bucket_scatter_a_kernel(
        const int* __restrict__ src, const int* __restrict__ dst, int E, int NB,
        int* __restrict__ bucket_pos, unsigned* __restrict__ pairs) {
    __shared__ int hist[512];
    __shared__ int base[512];
    int t = threadIdx.x;
    int c0 = blockIdx.x * CHUNK;
    int cend = min(c0 + CHUNK, E);
    for (int i = t; i < NB; i += 256) hist[i] = 0;
    __syncthreads();
    for (int i = c0 + t; i < cend; i += 256)
        atomicAdd(&hist[dst[i] >> BSHIFT], 1);
    __syncthreads();
    for (int i = t; i < NB; i += 256) {
        int h = hist[i];
        base[i] = (h > 0) ? atomicAdd(&bucket_pos[i], h) : 0;
        hist[i] = 0;  // reuse as local offset
    }
    __syncthreads();
    for (int i = c0 + t; i < cend; i += 256) {
        int d = dst[i];
        int b = d >> BSHIFT;
        int p = base[b] + atomicAdd(&hist[b], 1);
        pairs[p] = ((unsigned)(d & (BSIZE - 1)) << 24) | (unsigned)src[i];
    }
}

// phase B: one block per bucket. Fine histogram + exclusive scan in LDS -> writes row_start
// for this bucket's 256 nodes, then scatters srcs into the contiguous ~16KB window.
__global__ __launch_bounds__(256) void bucket_sort_kernel(const unsigned* __restrict__ pairs,
                                                          const int* __restrict__ coarse_start,
                                                          int N, int* __restrict__ row_start,
                                                          int* __restrict__ src_sorted) {
    __shared__ int hist[256];
    __shared__ int tmp[256];
    int b = blockIdx.x, t = threadIdx.x;
    int base = b << BSHIFT;
    int start = coarse_start[b];
    int end = coarse_start[b + 1];
    hist[t] = 0;
    __syncthreads();
    for (int i = start + t; i < end; i += 256)
        atomicAdd(&hist[pairs[i] >> 24], 1);
    __syncthreads();
    int v = hist[t];
    tmp[t] = v;
    __syncthreads();
    for (int d = 1; d < 256; d <<= 1) {
        int add = (t >= d) ? tmp[t - d] : 0;
        __syncthreads();
        tmp[t] += add;
        __syncthreads();
    }
    int ex = start + tmp[t] - v;  // exclusive prefix within bucket + bucket base
    if (base + t < N) row_start[base + t] = ex;
    hist[t] = ex;  // reuse as running position
    __syncthreads();
    for (int i = start + t; i < end; i += 256) {
        unsigned u = pairs[i];
        int p = atomicAdd(&hist[u >> 24], 1);
        src_sorted[p] = (int)(u & 0x00FFFFFFu);
    }
}

// ---------------- prep: fp32 -> fp16 feature copy ----------------

__global__ void conv_f16_kernel(const float* __restrict__ in, __half* __restrict__ out, int n4) {
    int i = blockIdx.x * blockDim.x + threadIdx.x;
    if (i >= n4) return;
    float4 v = ((const float4*)in)[i];
    __half2 a = __floats2half2_rn(v.x, v.y);
    __half2 b = __floats2half2_rn(v.z, v.w);
    uint2 o;
    o.x = __builtin_bit_cast(unsigned, a);
    o.y = __builtin_bit_cast(unsigned, b);
    ((uint2*)out)[i] = o;
}

// ---------------- prep: weight transpose fp32 [K=128][Nin] -> fp16 [Npad][128] ----------------

__global__ __launch_bounds__(256) void prep_weights_kernel(
        const float* __restrict__ w1, const float* __restrict__ w2,
        const float* __restrict__ w3, const float* __restrict__ w4,
        __half* __restrict__ w1t, __half* __restrict__ w2t,
        __half* __restrict__ w3t, __half* __restrict__ w4t) {
    __shared__ float lds[128 * 128];
    const float* in; __half* outp; int Nin, Npad;
    switch (blockIdx.x) {
        case 0:  in = w1; outp = w1t; Nin = 128; Npad = 128; break;
        case 1:  in = w2; outp = w2t; Nin = 128; Npad = 128; break;
        case 2:  in = w3; outp = w3t; Nin = 128; Npad = 128; break;
        default: in = w4; outp = w4t; Nin = 40;  Npad = 48;  break;
    }
    int t = threadIdx.x;
    int nf4 = 128 * Nin / 4;
    for (int i = t; i < nf4; i += 256)
        ((float4*)lds)[i] = ((const float4*)in)[i];
    __syncthreads();
    int total = Npad * 64;
    for (int i = t; i < total; i += 256) {
        int n = i >> 6, k2 = (i & 63) * 2;
        float lo = 0.f, hi = 0.f;
        if (n < Nin) {
            lo = lds[k2 * Nin + n];
            hi = lds[(k2 + 1) * Nin + n];
        }
        __half2 h = __floats2half2_rn(lo, hi);
        ((unsigned*)outp)[i] = __builtin_bit_cast(unsigned, h);
    }
}

// ---------------- aggregation (fp16 feat, fp32 accumulate) ----------------

__global__ __launch_bounds__(256) void agg_f16_kernel(const __half* __restrict__ feat,
        const int* __restrict__ row_start, const int* __restrict__ src_sorted,
        const float* __restrict__ eps_ptr, __half* __restrict__ out, int N) {
    int wid = (int)((blockIdx.x * blockDim.x + threadIdx.x) >> 6);
    int lane = threadIdx.x & 63;
    if (wid >= N) return;
    int q = lane >> 4, l16 = lane & 15;
    int s = row_start[wid], e = row_start[wid + 1];
    float a[8] = {0.f, 0.f, 0.f, 0.f, 0.f, 0.f, 0.f, 0.f};
    float b[8] = {0.f, 0.f, 0.f, 0.f, 0.f, 0.f, 0.f, 0.f};
    int i = s + q;
    for (; i + 4 < e; i += 8) {
        int sv0 = src_sorted[i];
        int sv1 = src_sorted[i + 4];
        uint4 u0 = *(((const uint4*)(feat + (size_t)sv0 * F)) + l16);
        uint4 u1 = *(((const uint4*)(feat + (size_t)sv1 * F)) + l16);
        float2 f0 = __half22float2(__builtin_bit_cast(__half2, u0.x));
        float2 f1 = __half22float2(__builtin_bit_cast(__half2, u0.y));
        float2 f2 = __half22float2(__builtin_bit_cast(__half2, u0.z));
        float2 f3 = __half22float2(__builtin_bit_cast(__half2, u0.w));
        a[0] += f0.x; a[1] += f0.y; a[2] += f1.x; a[3] += f1.y;
        a[4] += f2.x; a[5] += f2.y; a[6] += f3.x; a[7] += f3.y;
        float2 g0 = __half22float2(__builtin_bit_cast(__half2, u1.x));
        float2 g1 = __half22float2(__builtin_bit_cast(__half2, u1.y));
        float2 g2 = __half22float2(__builtin_bit_cast(__half2, u1.z));
        float2 g3 = __half22float2(__builtin_bit_cast(__half2, u1.w));
        b[0] += g0.x; b[1] += g0.y; b[2] += g1.x; b[3] += g1.y;
        b[4] += g2.x; b[5] += g2.y; b[6] += g3.x; b[7] += g3.y;
    }
    if (i < e) {
        int sv = src_sorted[i];
        uint4 u = *(((const uint4*)(feat + (size_t)sv * F)) + l16);
        float2 f0 = __half22float2(__builtin_bit_cast(__half2, u.x));
        float2 f1 = __half22float2(__builtin_bit_cast(__half2, u.y));
        float2 f2 = __half22float2(__builtin_bit_cast(__half2, u.z));
        float2 f3 = __half22float2(__builtin_bit_cast(__half2, u.w));
        a[0] += f0.x; a[1] += f0.y; a[2] += f1.x; a[3] += f1.y;
        a[4] += f2.x; a[5] += f2.y; a[6] += f3.x; a[7] += f3.y;
    }
#pragma unroll
    for (int j = 0; j < 8; ++j) {
        a[j] += b[j];
        a[j] += __shfl_xor(a[j], 16);
        a[j] += __shfl_xor(a[j], 32);
    }
    if (q == 0) {
        float ep1 = 1.0f + *eps_ptr;
        uint4 u = *(((const uint4*)(feat + (size_t)wid * F)) + l16);
        float2 s0 = __half22float2(__builtin_bit_cast(__half2, u.x));
        float2 s1 = __half22float2(__builtin_bit_cast(__half2, u.y));
        float2 s2 = __half22float2(__builtin_bit_cast(__half2, u.z));
        float2 s3 = __half22float2(__builtin_bit_cast(__half2, u.w));
        a[0] = fmaf(ep1, s0.x, a[0]); a[1] = fmaf(ep1, s0.y, a[1]);
        a[2] = fmaf(ep1, s1.x, a[2]); a[3] = fmaf(ep1, s1.y, a[3]);
        a[4] = fmaf(ep1, s2.x, a[4]); a[5] = fmaf(ep1, s2.y, a[5]);
        a[6] = fmaf(ep1, s3.x, a[6]); a[7] = fmaf(ep1, s3.y, a[7]);
        uint4 ou;
        ou.x = __builtin_bit_cast(unsigned, __floats2half2_rn(a[0], a[1]));
        ou.y = __builtin_bit_cast(unsigned, __floats2half2_rn(a[2], a[3]));
        ou.z = __builtin_bit_cast(unsigned, __floats2half2_rn(a[4], a[5]));
        ou.w = __builtin_bit_cast(unsigned, __floats2half2_rn(a[6], a[7]));
        *(((uint4*)(out + (size_t)wid * F)) + l16) = ou;
    }
}

// ---------------- mlp1 (MFMA): out = relu(relu(A@w1+b1)@w2+b2), fp16 in/out ----------------

__global__ __launch_bounds__(256) void mlp1_mfma_kernel(const __half* __restrict__ A,
        const __half* __restrict__ w1t, const float* __restrict__ b1,
        const __half* __restrict__ w2t, const float* __restrict__ b2,
        __half* __restrict__ out, int N) {
    __shared__ __half ldsA[64 * LDH];
    __shared__ __half ldsW[128 * LDH];
    __shared__ float ldsB[256];
    int t = threadIdx.x;
    int wave = t >> 6, lane = t & 63, quad = lane >> 4, l16 = lane & 15;
    int br = blockIdx.x * 64;
    if (t < 128) ldsB[t] = b1[t];
    else         ldsB[t] = b2[t - 128];
    for (int i = t; i < 1024; i += 256) {
        int r = i >> 4, c = i & 15;
        int gr = br + r;
        uint4 v = make_uint4(0u, 0u, 0u, 0u);
        if (gr < N) v = *((const uint4*)(A + (size_t)gr * F + c * 8));
        *((uint4*)&ldsA[r * LDH + c * 8]) = v;
    }
    for (int i = t; i < 2048; i += 256) {
        int r = i >> 4, c = i & 15;
        *((uint4*)&ldsW[r * LDH + c * 8]) = *((const uint4*)(w1t + r * 128 + c * 8));
    }
    __syncthreads();

    int ct0 = wave * 2;
    float4v acc[4][2];
    float4v zero = {0.f, 0.f, 0.f, 0.f};
#pragma unroll
    for (int i = 0; i < 4; ++i)
#pragma unroll
        for (int j = 0; j < 2; ++j) acc[i][j] = zero;

#pragma unroll
    for (int ks = 0; ks < 4; ++ks) {
        half8 af[4], wf[2];
#pragma unroll
        for (int i = 0; i < 4; ++i)
            af[i] = *((const half8*)&ldsA[(i * 16 + l16) * LDH + ks * 32 + quad * 8]);
#pragma unroll
        for (int j = 0; j < 2; ++j)
            wf[j] = *((const half8*)&ldsW[((ct0 + j) * 16 + l16) * LDH + ks * 32 + quad * 8]);
#pragma unroll
        for (int i = 0; i < 4; ++i)
#pragma unroll
            for (int j = 0; j < 2; ++j)
                acc[i][j] = __builtin_amdgcn_mfma_f32_16x16x32_f16(wf[j], af[i], acc[i][j], 0, 0, 0);
    }
    __syncthreads();
#pragma unroll
    for (int j = 0; j < 2; ++j) {
        int c = ct0 + j;
        float4 bb = *((const float4*)&ldsB[c * 16 + quad * 4]);
#pragma unroll
        for (int i = 0; i < 4; ++i) {
            float v0 = acc[i][j][0] + bb.x; v0 = v0 > 0.f ? v0 : 0.f;
            float v1 = acc[i][j][1] + bb.y; v1 = v1 > 0.f ? v1 : 0.f;
            float v2 = acc[i][j][2] + bb.z; v2 = v2 > 0.f ? v2 : 0.f;
            float v3 = acc[i][j][3] + bb.w; v3 = v3 > 0.f ? v3 : 0.f;
            __half2 h0 = __floats2half2_rn(v0, v1);
            __half2 h1 = __floats2half2_rn(v2, v3);
            uint2 o;
            o.x = __builtin_bit_cast(unsigned, h0);
            o.y = __builtin_bit_cast(unsigned, h1);
            *((uint2*)&ldsA[(i * 16 + l16) * LDH + c * 16 + quad * 4]) = o;
        }
    }
    for (int i = t; i < 2048; i += 256) {
        int r = i >> 4, c = i & 15;
        *((uint4*)&ldsW[r * LDH + c * 8]) = *((const uint4*)(w2t + r * 128 + c * 8));
    }
    __syncthreads();

#pragma unroll
    for (int i = 0; i < 4; ++i)
#pragma unroll
        for (int j = 0; j < 2; ++j) acc[i][j] = zero;
#pragma unroll
    for (int ks = 0; ks < 4; ++ks) {
        half8 af[4], wf[2];
#pragma unroll
        for (int i = 0; i < 4; ++i)
            af[i] = *((const half8*)&ldsA[(i * 16 + l16) * LDH + ks * 32 + quad * 8]);
#pragma unroll
        for (int j = 0; j < 2; ++j)
            wf[j] = *((const half8*)&ldsW[((ct0 + j) * 16 + l16) * LDH + ks * 32 + quad * 8]);
#pragma unroll
        for (int i = 0; i < 4; ++i)
#pragma unroll
            for (int j = 0; j < 2; ++j)
                acc[i][j] = __builtin_amdgcn_mfma_f32_16x16x32_f16(wf[j], af[i], acc[i][j], 0, 0, 0);
    }
    __syncthreads();
#pragma unroll
    for (int j = 0; j < 2; ++j) {
        int c = ct0 + j;
        float4 bb = *((const float4*)&ldsB[128 + c * 16 + quad * 4]);
#pragma unroll
        for (int i = 0; i < 4; ++i) {
            float v0 = acc[i][j][0] + bb.x; v0 = v0 > 0.f ? v0 : 0.f;
            float v1 = acc[i][j][1] + bb.y; v1 = v1 > 0.f ? v1 : 0.f;
            float v2 = acc[i][j][2] + bb.z; v2 = v2 > 0.f ? v2 : 0.f;
            float v3 = acc[i][j][3] + bb.w; v3 = v3 > 0.f ? v3 : 0.f;
            __half2 h0 = __floats2half2_rn(v0, v1);
            __half2 h1 = __floats2half2_rn(v2, v3);
            uint2 o;
            o.x = __builtin_bit_cast(unsigned, h0);
            o.y = __builtin_bit_cast(unsigned, h1);
            *((uint2*)&ldsA[(i * 16 + l16) * LDH + c * 16 + quad * 4]) = o;
        }
    }
    __syncthreads();
    for (int i = t; i < 1024; i += 256) {
        int r = i >> 4, c = i & 15;
        int gr = br + r;
        if (gr < N)
            *((uint4*)(out + (size_t)gr * F + c * 8)) = *((const uint4*)&ldsA[r * LDH + c * 8]);
    }
}

// ---------------- mlp2 (MFMA): out = log_softmax(relu(A@w3+b3)@w4+b4) ----------------

__global__ __launch_bounds__(256) void mlp2_mfma_kernel(const __half* __restrict__ A,
        const __half* __restrict__ w3t, const float* __restrict__ b3,
        const __half* __restrict__ w4t, const float* __restrict__ b4,
        float* __restrict__ out, int N) {
    __shared__ __half ldsA[64 * LDH];
    __shared__ __half ldsW[128 * LDH];
    __shared__ float ldsB[176];
    int t = threadIdx.x;
    int wave = t >> 6, lane = t & 63, quad = lane >> 4, l16 = lane & 15;
    int br = blockIdx.x * 64;
    if (t < 128) ldsB[t] = b3[t];
    else if (t < 176) ldsB[t] = (t - 128 < C) ? b4[t - 128] : 0.f;
    for (int i = t; i < 1024; i += 256) {
        int r = i >> 4, c = i & 15;
        int gr = br + r;
        uint4 v = make_uint4(0u, 0u, 0u, 0u);
        if (gr < N) v = *((const uint4*)(A + (size_t)gr * F + c * 8));
        *((uint4*)&ldsA[r * LDH + c * 8]) = v;
    }
    for (int i = t; i < 2048; i += 256) {
        int r = i >> 4, c = i & 15;
        *((uint4*)&ldsW[r * LDH + c * 8]) = *((const uint4*)(w3t + r * 128 + c * 8));
    }
    __syncthreads();

    int ct0 = wave * 2;
    float4v acc[4][2];
    float4v zero = {0.f, 0.f, 0.f, 0.f};
#pragma unroll
    for (int i = 0; i < 4; ++i)
#pragma unroll
        for (int j = 0; j < 2; ++j) acc[i][j] = zero;
#pragma unroll
    for (int ks = 0; ks < 4; ++ks) {
        half8 af[4], wf[2];
#pragma unroll
        for (int i = 0; i < 4; ++i)
            af[i] = *((const half8*)&ldsA[(i * 16 + l16) * LDH + ks * 32 + quad * 8]);
#pragma unroll
        for (int j = 0; j < 2; ++j)
            wf[j] = *((const half8*)&ldsW[((ct0 + j) * 16 + l16) * LDH + ks * 32 + quad * 8]);
#pragma unroll
        for (int i = 0; i < 4; ++i)
#pragma unroll
            for (int j = 0; j < 2; ++j)
                acc[i][j] = __builtin_amdgcn_mfma_f32_16x16x32_f16(wf[j], af[i], acc[i][j], 0, 0, 0);
    }
    __syncthreads();
#pragma unroll
    for (int j = 0; j < 2; ++j) {
        int c = ct0 + j;
        float4 bb = *((const float4*)&ldsB[c * 16 + quad * 4]);
#pragma unroll
        for (int i = 0; i < 4; ++i) {
            float v0 = acc[i][j][0] + bb.x; v0 = v0 > 0.f ? v0 : 0.f;
            float v1 = acc[i][j][1] + bb.y; v1 = v1 > 0.f ? v1 : 0.f;
            float v2 = acc[i][j][2] + bb.z; v2 = v2 > 0.f ? v2 : 0.f;
            float v3 = acc[i][j][3] + bb.w; v3 = v3 > 0.f ? v3 : 0.f;
            __half2 h0 = __floats2half2_rn(v0, v1);
            __half2 h1 = __floats2half2_rn(v2, v3);
            uint2 o;
            o.x = __builtin_bit_cast(unsigned, h0);
            o.y = __builtin_bit_cast(unsigned, h1);
            *((uint2*)&ldsA[(i * 16 + l16) * LDH + c * 16 + quad * 4]) = o;
        }
    }
    for (int i = t; i < 768; i += 256) {
        int r = i >> 4, c = i & 15;
        *((uint4*)&ldsW[r * LDH + c * 8]) = *((const uint4*)(w4t + r * 128 + c * 8));
    }
    __syncthreads();

    float4v acc4[3];
#pragma unroll
    for (int c = 0; c < 3; ++c) acc4[c] = zero;
#pragma unroll
    for (int ks = 0; ks < 4; ++ks) {
        half8 af = *((const half8*)&ldsA[(wave * 16 + l16) * LDH + ks * 32 + quad * 8]);
#pragma unroll
        for (int c = 0; c < 3; ++c) {
            half8 wf = *((const half8*)&ldsW[(c * 16 + l16) * LDH + ks * 32 + quad * 8]);
            acc4[c] = __builtin_amdgcn_mfma_f32_16x16x32_f16(wf, af, acc4[c], 0, 0, 0);
        }
    }
    float lv[3][4];
#pragma unroll
    for (int c = 0; c < 3; ++c) {
        float4 bb = *((const float4*)&ldsB[128 + c * 16 + quad * 4]);
        lv[c][0] = acc4[c][0] + bb.x;
        lv[c][1] = acc4[c][1] + bb.y;
        lv[c][2] = acc4[c][2] + bb.z;
        lv[c][3] = acc4[c][3] + bb.w;
    }
    bool tile2ok = (quad < 2);
    float m = -1e30f;
#pragma unroll
    for (int c = 0; c < 3; ++c) {
        if (c == 2 && !tile2ok) continue;
#pragma unroll
        for (int r = 0; r < 4; ++r) m = fmaxf(m, lv[c][r]);
    }
    m = fmaxf(m, __shfl_xor(m, 16));
    m = fmaxf(m, __shfl_xor(m, 32));
    float ssum = 0.f;
#pragma unroll
    for (int c = 0; c < 3; ++c) {
        if (c == 2 && !tile2ok) continue;
#pragma unroll
        for (int r = 0; r < 4; ++r) ssum += __expf(lv[c][r] - m);
    }
    ssum += __shfl_xor(ssum, 16);
    ssum += __shfl_xor(ssum, 32);
    float L = m + __logf(ssum);
    int node = br + wave * 16 + l16;
    if (node < N) {
#pragma unroll
        for (int c = 0; c < 3; ++c) {
            if (c == 2 && !tile2ok) continue;
            float4 o = make_float4(lv[c][0] - L, lv[c][1] - L, lv[c][2] - L, lv[c][3] - L);
            *((float4*)(out + (size_t)node * C + c * 16 + quad * 4)) = o;
        }
    }
}

// ---------------- launch ----------------

extern "C" void kernel_launch(void* const* d_in, const int* in_sizes, int n_in,
                              void* d_out, int out_size, void* d_ws, size_t ws_size,
                              hipStream_t stream) {
    const float* x    = (const float*)d_in[0];
    const int*   ei   = (const int*)d_in[1];
    const float* eps1 = (const float*)d_in[2];
    const float* w1   = (const float*)d_in[3];
    const float* b1   = (const float*)d_in[4];
    const float* w2   = (const float*)d_in[5];
    const float* b2   = (const float*)d_in[6];
    const float* eps2 = (const float*)d_in[7];
    const float* w3   = (const float*)d_in[8];
    const float* b3   = (const float*)d_in[9];
    const float* w4   = (const float*)d_in[10];
    const float* b4   = (const float*)d_in[11];
    float* out = (float*)d_out;

    int N = in_sizes[0] / F;       // 100000
    int E = in_sizes[1] / 2;       // 1600000
    const int* src = ei;
    const int* dst = ei + E;

    int NB = (N + BSIZE - 1) >> BSHIFT;   // 391 coarse buckets (<= 512)
    int BA = (E + CHUNK - 1) / CHUNK;     // chunked blocks over edges

    // workspace layout
    __half* x_h  = (__half*)d_ws;                   // N*F
    __half* h0_h = x_h + (size_t)N * F;             // N*F
    __half* h_h  = h0_h + (size_t)N * F;            // N*F
    __half* w1t  = h_h + (size_t)N * F;             // 128*128
    __half* w2t  = w1t + 128 * 128;
    __half* w3t  = w2t + 128 * 128;
    __half* w4t  = w3t + 128 * 128;                 // 48*128
    unsigned* pairs   = (unsigned*)(w4t + 48 * 128); // E
    int* row_start    = (int*)(pairs + E);          // N+1
    int* src_sorted   = row_start + (N + 1);        // E
    int* coarse_count = src_sorted + E;             // 512
    int* coarse_start = coarse_count + 512;         // 513
    int* bucket_pos   = coarse_start + 513;         // 512

    // prep: fp16 conversions + weight transposes
    int n4 = N * F / 4;
    conv_f16_kernel<<<(n4 + 255) / 256, 256, 0, stream>>>(x, x_h, n4);
    prep_weights_kernel<<<4, 256, 0, stream>>>(w1, w2, w3, w4, w1t, w2t, w3t, w4t);

    // CSR build: coarse hist -> coarse scan -> bucket scatter -> per-bucket LDS sort
    hipMemsetAsync(coarse_count, 0, (size_t)NB * sizeof(int), stream);
    coarse_hist_kernel<<<BA, 256, 0, stream>>>(dst, E, NB, coarse_count);
    coarse_scan_kernel<<<1, 512, 0, stream>>>(coarse_count, NB, E, coarse_start, bucket_pos,
                                              row_start, N);
    bucket_scatter_a_kernel<<<BA, 256, 0, stream>>>(src, dst, E, NB, bucket_pos, pairs);
    bucket_sort_kernel<<<NB, 256, 0, stream>>>(pairs, coarse_start, N, row_start, src_sorted);

    // layer 1
    agg_f16_kernel<<<(N + 3) / 4, 256, 0, stream>>>(x_h, row_start, src_sorted, eps1, h0_h, N);
    mlp1_mfma_kernel<<<(N + 63) / 64, 256, 0, stream>>>(h0_h, w1t, b1, w2t, b2, h_h, N);
    // layer 2
    agg_f16_kernel<<<(N + 3) / 4, 256, 0, stream>>>(h_h, row_start, src_sorted, eps2, h0_h, N);
    mlp2_mfma_kernel<<<(N + 63) / 64, 256, 0, stream>>>(h0_h, w3t, b3, w4t, b4, out, N);
}

// Round 7
// 354.571 us; speedup vs baseline: 2.6859x; 1.0158x over previous
//
#include <hip/hip_runtime.h>
#include <hip/hip_fp16.h>
#include <math.h>

constexpr int F = 128;
constexpr int C = 40;
constexpr int LDH = 136;   // padded LDS stride in halves
constexpr int BSHIFT = 8;  // 256 dst per coarse bucket
constexpr int BSIZE = 1 << BSHIFT;
constexpr int CHUNK = 8192;  // edges per histogram/scatter block

typedef __attribute__((ext_vector_type(8))) _Float16 half8;
typedef __attribute__((ext_vector_type(4))) float float4v;

// ---------------- CSR build (coarse-bucket pipeline) ----------------

__global__ __launch_bounds__(256) void coarse_hist_kernel(const int* __restrict__ dst, int E, int NB,
                                                          int* __restrict__ coarse_count) {
    __shared__ int hist[512];
    int t = threadIdx.x;
    int c0 = blockIdx.x * CHUNK;
    int cend = min(c0 + CHUNK, E);
    for (int i = t; i < NB; i += 256) hist[i] = 0;
    __syncthreads();
    for (int i = c0 + t; i < cend; i += 256)
        atomicAdd(&hist[dst[i] >> BSHIFT], 1);
    __syncthreads();
    for (int i = t; i < NB; i += 256)
        if (hist[i]) atomicAdd(&coarse_count[i], hist[i]);
}

__global__ __launch_bounds__(512) void coarse_scan_kernel(const int* __restrict__ coarse_count,
                                                          int NB, int E,
                                                          int* __restrict__ coarse_start,
                                                          int* __restrict__ bucket_pos,
                                                          int* __restrict__ row_start, int N) {
    __shared__ int tmp[512];
    int t = threadIdx.x;
    int v = (t < NB) ? coarse_count[t] : 0;
    tmp[t] = v;
    __syncthreads();
    for (int d = 1; d < 512; d <<= 1) {
        int add = (t >= d) ? tmp[t - d] : 0;
        __syncthreads();
        tmp[t] += add;
        __syncthreads();
    }
    if (t < NB) {
        int ex = tmp[t] - v;
        coarse_start[t] = ex;
        bucket_pos[t] = ex;
    }
    if (t == 0) {
        coarse_start[NB] = E;
        row_start[N] = E;
    }
}

// phase A: per-block LDS histogram -> one global atomic per (block,bucket) -> packed scatter.
__global__ __launch_bounds__(256) void bucket_scatter_a_kernel(
        const int* __restrict__ src, const int* __restrict__ dst, int E, int NB,
        int* __restrict__ bucket_pos, unsigned* __restrict__ pairs) {
    __shared__ int hist[512];
    __shared__ int base[512];
    int t = threadIdx.x;
    int c0 = blockIdx.x * CHUNK;
    int cend = min(c0 + CHUNK, E);
    for (int i = t; i < NB; i += 256) hist[i] = 0;
    __syncthreads();
    for (int i = c0 + t; i < cend; i += 256)
        atomicAdd(&hist[dst[i] >> BSHIFT], 1);
    __syncthreads();
    for (int i = t; i < NB; i += 256) {
        int h = hist[i];
        base[i] = (h > 0) ? atomicAdd(&bucket_pos[i], h) : 0;
        hist[i] = 0;  // reuse as local offset
    }
    __syncthreads();
    for (int i = c0 + t; i < cend; i += 256) {
        int d = dst[i];
        int b = d >> BSHIFT;
        int p = base[b] + atomicAdd(&hist[b], 1);
        pairs[p] = ((unsigned)(d & (BSIZE - 1)) << 24) | (unsigned)src[i];
    }
}

// phase B: one block per bucket; fine hist + scan in LDS -> row_start + contiguous scatter
__global__ __launch_bounds__(256) void bucket_sort_kernel(const unsigned* __restrict__ pairs,
                                                          const int* __restrict__ coarse_start,
                                                          int N, int* __restrict__ row_start,
                                                          int* __restrict__ src_sorted) {
    __shared__ int hist[256];
    __shared__ int tmp[256];
    int b = blockIdx.x, t = threadIdx.x;
    int base = b << BSHIFT;
    int start = coarse_start[b];
    int end = coarse_start[b + 1];
    hist[t] = 0;
    __syncthreads();
    for (int i = start + t; i < end; i += 256)
        atomicAdd(&hist[pairs[i] >> 24], 1);
    __syncthreads();
    int v = hist[t];
    tmp[t] = v;
    __syncthreads();
    for (int d = 1; d < 256; d <<= 1) {
        int add = (t >= d) ? tmp[t - d] : 0;
        __syncthreads();
        tmp[t] += add;
        __syncthreads();
    }
    int ex = start + tmp[t] - v;
    if (base + t < N) row_start[base + t] = ex;
    hist[t] = ex;
    __syncthreads();
    for (int i = start + t; i < end; i += 256) {
        unsigned u = pairs[i];
        int p = atomicAdd(&hist[u >> 24], 1);
        src_sorted[p] = (int)(u & 0x00FFFFFFu);
    }
}

// ---------------- prep: fp32 -> fp16 feature copy (+ zero coarse_count) ----------------

__global__ void conv_f16_kernel(const float* __restrict__ in, __half* __restrict__ out, int n4,
                                int* __restrict__ coarse_count, int NB) {
    int i = blockIdx.x * blockDim.x + threadIdx.x;
    if (blockIdx.x == 0) {
        for (int j = threadIdx.x; j < NB; j += 256) coarse_count[j] = 0;
    }
    if (i >= n4) return;
    float4 v = ((const float4*)in)[i];
    __half2 a = __floats2half2_rn(v.x, v.y);
    __half2 b = __floats2half2_rn(v.z, v.w);
    uint2 o;
    o.x = __builtin_bit_cast(unsigned, a);
    o.y = __builtin_bit_cast(unsigned, b);
    ((uint2*)out)[i] = o;
}

// ---------------- prep: weight transpose fp32 [K=128][Nin] -> fp16 [Npad][128] ----------------

__global__ __launch_bounds__(256) void prep_weights_kernel(
        const float* __restrict__ w1, const float* __restrict__ w2,
        const float* __restrict__ w3, const float* __restrict__ w4,
        __half* __restrict__ w1t, __half* __restrict__ w2t,
        __half* __restrict__ w3t, __half* __restrict__ w4t) {
    __shared__ float lds[128 * 128];
    const float* in; __half* outp; int Nin, Npad;
    switch (blockIdx.x) {
        case 0:  in = w1; outp = w1t; Nin = 128; Npad = 128; break;
        case 1:  in = w2; outp = w2t; Nin = 128; Npad = 128; break;
        case 2:  in = w3; outp = w3t; Nin = 128; Npad = 128; break;
        default: in = w4; outp = w4t; Nin = 40;  Npad = 48;  break;
    }
    int t = threadIdx.x;
    int nf4 = 128 * Nin / 4;
    for (int i = t; i < nf4; i += 256)
        ((float4*)lds)[i] = ((const float4*)in)[i];
    __syncthreads();
    int total = Npad * 64;
    for (int i = t; i < total; i += 256) {
        int n = i >> 6, k2 = (i & 63) * 2;
        float lo = 0.f, hi = 0.f;
        if (n < Nin) {
            lo = lds[k2 * Nin + n];
            hi = lds[(k2 + 1) * Nin + n];
        }
        __half2 h = __floats2half2_rn(lo, hi);
        ((unsigned*)outp)[i] = __builtin_bit_cast(unsigned, h);
    }
}

// ---------------- aggregation (fp16 feat, packed fp16 accumulate, fp32 merge) ----------------
// one wave per node; 4 quarter-waves, each covers the full 128-feat row (uint4 = 8 halves/lane
// over 16 lanes) and processes every 4th edge; 2 banks of half2 accumulators (v_pk_add_f16),
// each bank sums ~deg/8 values; cross-bank + cross-quarter merge in fp32.

__global__ __launch_bounds__(256) void agg_f16_kernel(const __half* __restrict__ feat,
        const int* __restrict__ row_start, const int* __restrict__ src_sorted,
        const float* __restrict__ eps_ptr, __half* __restrict__ out, int N) {
    int wid = (int)((blockIdx.x * blockDim.x + threadIdx.x) >> 6);
    int lane = threadIdx.x & 63;
    if (wid >= N) return;
    int q = lane >> 4, l16 = lane & 15;
    int s = row_start[wid], e = row_start[wid + 1];
    __half2 A0, A1, A2, A3, B0, B1, B2, B3;
    A0 = A1 = A2 = A3 = B0 = B1 = B2 = B3 = __builtin_bit_cast(__half2, 0u);
    int i = s + q;
    for (; i + 4 < e; i += 8) {
        int sv0 = src_sorted[i];
        int sv1 = src_sorted[i + 4];
        uint4 u0 = *(((const uint4*)(feat + (size_t)sv0 * F)) + l16);
        uint4 u1 = *(((const uint4*)(feat + (size_t)sv1 * F)) + l16);
        A0 = __hadd2(A0, __builtin_bit_cast(__half2, u0.x));
        A1 = __hadd2(A1, __builtin_bit_cast(__half2, u0.y));
        A2 = __hadd2(A2, __builtin_bit_cast(__half2, u0.z));
        A3 = __hadd2(A3, __builtin_bit_cast(__half2, u0.w));
        B0 = __hadd2(B0, __builtin_bit_cast(__half2, u1.x));
        B1 = __hadd2(B1, __builtin_bit_cast(__half2, u1.y));
        B2 = __hadd2(B2, __builtin_bit_cast(__half2, u1.z));
        B3 = __hadd2(B3, __builtin_bit_cast(__half2, u1.w));
    }
    if (i < e) {
        int sv = src_sorted[i];
        uint4 u = *(((const uint4*)(feat + (size_t)sv * F)) + l16);
        A0 = __hadd2(A0, __builtin_bit_cast(__half2, u.x));
        A1 = __hadd2(A1, __builtin_bit_cast(__half2, u.y));
        A2 = __hadd2(A2, __builtin_bit_cast(__half2, u.z));
        A3 = __hadd2(A3, __builtin_bit_cast(__half2, u.w));
    }
    // fp32 merge of the two banks
    float a[8];
    {
        float2 fa, fb;
        fa = __half22float2(A0); fb = __half22float2(B0); a[0] = fa.x + fb.x; a[1] = fa.y + fb.y;
        fa = __half22float2(A1); fb = __half22float2(B1); a[2] = fa.x + fb.x; a[3] = fa.y + fb.y;
        fa = __half22float2(A2); fb = __half22float2(B2); a[4] = fa.x + fb.x; a[5] = fa.y + fb.y;
        fa = __half22float2(A3); fb = __half22float2(B3); a[6] = fa.x + fb.x; a[7] = fa.y + fb.y;
    }
#pragma unroll
    for (int j = 0; j < 8; ++j) {
        a[j] += __shfl_xor(a[j], 16);
        a[j] += __shfl_xor(a[j], 32);
    }
    if (q == 0) {
        float ep1 = 1.0f + *eps_ptr;
        uint4 u = *(((const uint4*)(feat + (size_t)wid * F)) + l16);
        float2 s0 = __half22float2(__builtin_bit_cast(__half2, u.x));
        float2 s1 = __half22float2(__builtin_bit_cast(__half2, u.y));
        float2 s2 = __half22float2(__builtin_bit_cast(__half2, u.z));
        float2 s3 = __half22float2(__builtin_bit_cast(__half2, u.w));
        a[0] = fmaf(ep1, s0.x, a[0]); a[1] = fmaf(ep1, s0.y, a[1]);
        a[2] = fmaf(ep1, s1.x, a[2]); a[3] = fmaf(ep1, s1.y, a[3]);
        a[4] = fmaf(ep1, s2.x, a[4]); a[5] = fmaf(ep1, s2.y, a[5]);
        a[6] = fmaf(ep1, s3.x, a[6]); a[7] = fmaf(ep1, s3.y, a[7]);
        uint4 ou;
        ou.x = __builtin_bit_cast(unsigned, __floats2half2_rn(a[0], a[1]));
        ou.y = __builtin_bit_cast(unsigned, __floats2half2_rn(a[2], a[3]));
        ou.z = __builtin_bit_cast(unsigned, __floats2half2_rn(a[4], a[5]));
        ou.w = __builtin_bit_cast(unsigned, __floats2half2_rn(a[6], a[7]));
        *(((uint4*)(out + (size_t)wid * F)) + l16) = ou;
    }
}

// ---------------- mlp1 (MFMA): out = relu(relu(A@w1+b1)@w2+b2), fp16 in/out ----------------

__global__ __launch_bounds__(256) void mlp1_mfma_kernel(const __half* __restrict__ A,
        const __half* __restrict__ w1t, const float* __restrict__ b1,
        const __half* __restrict__ w2t, const float* __restrict__ b2,
        __half* __restrict__ out, int N) {
    __shared__ __half ldsA[64 * LDH];
    __shared__ __half ldsW[128 * LDH];
    __shared__ float ldsB[256];
    int t = threadIdx.x;
    int wave = t >> 6, lane = t & 63, quad = lane >> 4, l16 = lane & 15;
    int br = blockIdx.x * 64;
    if (t < 128) ldsB[t] = b1[t];
    else         ldsB[t] = b2[t - 128];
    for (int i = t; i < 1024; i += 256) {
        int r = i >> 4, c = i & 15;
        int gr = br + r;
        uint4 v = make_uint4(0u, 0u, 0u, 0u);
        if (gr < N) v = *((const uint4*)(A + (size_t)gr * F + c * 8));
        *((uint4*)&ldsA[r * LDH + c * 8]) = v;
    }
    for (int i = t; i < 2048; i += 256) {
        int r = i >> 4, c = i & 15;
        *((uint4*)&ldsW[r * LDH + c * 8]) = *((const uint4*)(w1t + r * 128 + c * 8));
    }
    __syncthreads();

    int ct0 = wave * 2;
    float4v acc[4][2];
    float4v zero = {0.f, 0.f, 0.f, 0.f};
#pragma unroll
    for (int i = 0; i < 4; ++i)
#pragma unroll
        for (int j = 0; j < 2; ++j) acc[i][j] = zero;

#pragma unroll
    for (int ks = 0; ks < 4; ++ks) {
        half8 af[4], wf[2];
#pragma unroll
        for (int i = 0; i < 4; ++i)
            af[i] = *((const half8*)&ldsA[(i * 16 + l16) * LDH + ks * 32 + quad * 8]);
#pragma unroll
        for (int j = 0; j < 2; ++j)
            wf[j] = *((const half8*)&ldsW[((ct0 + j) * 16 + l16) * LDH + ks * 32 + quad * 8]);
#pragma unroll
        for (int i = 0; i < 4; ++i)
#pragma unroll
            for (int j = 0; j < 2; ++j)
                acc[i][j] = __builtin_amdgcn_mfma_f32_16x16x32_f16(wf[j], af[i], acc[i][j], 0, 0, 0);
    }
    __syncthreads();
#pragma unroll
    for (int j = 0; j < 2; ++j) {
        int c = ct0 + j;
        float4 bb = *((const float4*)&ldsB[c * 16 + quad * 4]);
#pragma unroll
        for (int i = 0; i < 4; ++i) {
            float v0 = acc[i][j][0] + bb.x; v0 = v0 > 0.f ? v0 : 0.f;
            float v1 = acc[i][j][1] + bb.y; v1 = v1 > 0.f ? v1 : 0.f;
            float v2 = acc[i][j][2] + bb.z; v2 = v2 > 0.f ? v2 : 0.f;
            float v3 = acc[i][j][3] + bb.w; v3 = v3 > 0.f ? v3 : 0.f;
            __half2 h0 = __floats2half2_rn(v0, v1);
            __half2 h1 = __floats2half2_rn(v2, v3);
            uint2 o;
            o.x = __builtin_bit_cast(unsigned, h0);
            o.y = __builtin_bit_cast(unsigned, h1);
            *((uint2*)&ldsA[(i * 16 + l16) * LDH + c * 16 + quad * 4]) = o;
        }
    }
    for (int i = t; i < 2048; i += 256) {
        int r = i >> 4, c = i & 15;
        *((uint4*)&ldsW[r * LDH + c * 8]) = *((const uint4*)(w2t + r * 128 + c * 8));
    }
    __syncthreads();

#pragma unroll
    for (int i = 0; i < 4; ++i)
#pragma unroll
        for (int j = 0; j < 2; ++j) acc[i][j] = zero;
#pragma unroll
    for (int ks = 0; ks < 4; ++ks) {
        half8 af[4], wf[2];
#pragma unroll
        for (int i = 0; i < 4; ++i)
            af[i] = *((const half8*)&ldsA[(i * 16 + l16) * LDH + ks * 32 + quad * 8]);
#pragma unroll
        for (int j = 0; j < 2; ++j)
            wf[j] = *((const half8*)&ldsW[((ct0 + j) * 16 + l16) * LDH + ks * 32 + quad * 8]);
#pragma unroll
        for (int i = 0; i < 4; ++i)
#pragma unroll
            for (int j = 0; j < 2; ++j)
                acc[i][j] = __builtin_amdgcn_mfma_f32_16x16x32_f16(wf[j], af[i], acc[i][j], 0, 0, 0);
    }
    __syncthreads();
#pragma unroll
    for (int j = 0; j < 2; ++j) {
        int c = ct0 + j;
        float4 bb = *((const float4*)&ldsB[128 + c * 16 + quad * 4]);
#pragma unroll
        for (int i = 0; i < 4; ++i) {
            float v0 = acc[i][j][0] + bb.x; v0 = v0 > 0.f ? v0 : 0.f;
            float v1 = acc[i][j][1] + bb.y; v1 = v1 > 0.f ? v1 : 0.f;
            float v2 = acc[i][j][2] + bb.z; v2 = v2 > 0.f ? v2 : 0.f;
            float v3 = acc[i][j][3] + bb.w; v3 = v3 > 0.f ? v3 : 0.f;
            __half2 h0 = __floats2half2_rn(v0, v1);
            __half2 h1 = __floats2half2_rn(v2, v3);
            uint2 o;
            o.x = __builtin_bit_cast(unsigned, h0);
            o.y = __builtin_bit_cast(unsigned, h1);
            *((uint2*)&ldsA[(i * 16 + l16) * LDH + c * 16 + quad * 4]) = o;
        }
    }
    __syncthreads();
    for (int i = t; i < 1024; i += 256) {
        int r = i >> 4, c = i & 15;
        int gr = br + r;
        if (gr < N)
            *((uint4*)(out + (size_t)gr * F + c * 8)) = *((const uint4*)&ldsA[r * LDH + c * 8]);
    }
}

// ---------------- mlp2 (MFMA): out = log_softmax(relu(A@w3+b3)@w4+b4) ----------------

__global__ __launch_bounds__(256) void mlp2_mfma_kernel(const __half* __restrict__ A,
        const __half* __restrict__ w3t, const float* __restrict__ b3,
        const __half* __restrict__ w4t, const float* __restrict__ b4,
        float* __restrict__ out, int N) {
    __shared__ __half ldsA[64 * LDH];
    __shared__ __half ldsW[128 * LDH];
    __shared__ float ldsB[176];
    int t = threadIdx.x;
    int wave = t >> 6, lane = t & 63, quad = lane >> 4, l16 = lane & 15;
    int br = blockIdx.x * 64;
    if (t < 128) ldsB[t] = b3[t];
    else if (t < 176) ldsB[t] = (t - 128 < C) ? b4[t - 128] : 0.f;
    for (int i = t; i < 1024; i += 256) {
        int r = i >> 4, c = i & 15;
        int gr = br + r;
        uint4 v = make_uint4(0u, 0u, 0u, 0u);
        if (gr < N) v = *((const uint4*)(A + (size_t)gr * F + c * 8));
        *((uint4*)&ldsA[r * LDH + c * 8]) = v;
    }
    for (int i = t; i < 2048; i += 256) {
        int r = i >> 4, c = i & 15;
        *((uint4*)&ldsW[r * LDH + c * 8]) = *((const uint4*)(w3t + r * 128 + c * 8));
    }
    __syncthreads();

    int ct0 = wave * 2;
    float4v acc[4][2];
    float4v zero = {0.f, 0.f, 0.f, 0.f};
#pragma unroll
    for (int i = 0; i < 4; ++i)
#pragma unroll
        for (int j = 0; j < 2; ++j) acc[i][j] = zero;
#pragma unroll
    for (int ks = 0; ks < 4; ++ks) {
        half8 af[4], wf[2];
#pragma unroll
        for (int i = 0; i < 4; ++i)
            af[i] = *((const half8*)&ldsA[(i * 16 + l16) * LDH + ks * 32 + quad * 8]);
#pragma unroll
        for (int j = 0; j < 2; ++j)
            wf[j] = *((const half8*)&ldsW[((ct0 + j) * 16 + l16) * LDH + ks * 32 + quad * 8]);
#pragma unroll
        for (int i = 0; i < 4; ++i)
#pragma unroll
            for (int j = 0; j < 2; ++j)
                acc[i][j] = __builtin_amdgcn_mfma_f32_16x16x32_f16(wf[j], af[i], acc[i][j], 0, 0, 0);
    }
    __syncthreads();
#pragma unroll
    for (int j = 0; j < 2; ++j) {
        int c = ct0 + j;
        float4 bb = *((const float4*)&ldsB[c * 16 + quad * 4]);
#pragma unroll
        for (int i = 0; i < 4; ++i) {
            float v0 = acc[i][j][0] + bb.x; v0 = v0 > 0.f ? v0 : 0.f;
            float v1 = acc[i][j][1] + bb.y; v1 = v1 > 0.f ? v1 : 0.f;
            float v2 = acc[i][j][2] + bb.z; v2 = v2 > 0.f ? v2 : 0.f;
            float v3 = acc[i][j][3] + bb.w; v3 = v3 > 0.f ? v3 : 0.f;
            __half2 h0 = __floats2half2_rn(v0, v1);
            __half2 h1 = __floats2half2_rn(v2, v3);
            uint2 o;
            o.x = __builtin_bit_cast(unsigned, h0);
            o.y = __builtin_bit_cast(unsigned, h1);
            *((uint2*)&ldsA[(i * 16 + l16) * LDH + c * 16 + quad * 4]) = o;
        }
    }
    for (int i = t; i < 768; i += 256) {
        int r = i >> 4, c = i & 15;
        *((uint4*)&ldsW[r * LDH + c * 8]) = *((const uint4*)(w4t + r * 128 + c * 8));
    }
    __syncthreads();

    float4v acc4[3];
#pragma unroll
    for (int c = 0; c < 3; ++c) acc4[c] = zero;
#pragma unroll
    for (int ks = 0; ks < 4; ++ks) {
        half8 af = *((const half8*)&ldsA[(wave * 16 + l16) * LDH + ks * 32 + quad * 8]);
#pragma unroll
        for (int c = 0; c < 3; ++c) {
            half8 wf = *((const half8*)&ldsW[(c * 16 + l16) * LDH + ks * 32 + quad * 8]);
            acc4[c] = __builtin_amdgcn_mfma_f32_16x16x32_f16(wf, af, acc4[c], 0, 0, 0);
        }
    }
    float lv[3][4];
#pragma unroll
    for (int c = 0; c < 3; ++c) {
        float4 bb = *((const float4*)&ldsB[128 + c * 16 + quad * 4]);
        lv[c][0] = acc4[c][0] + bb.x;
        lv[c][1] = acc4[c][1] + bb.y;
        lv[c][2] = acc4[c][2] + bb.z;
        lv[c][3] = acc4[c][3] + bb.w;
    }
    bool tile2ok = (quad < 2);
    float m = -1e30f;
#pragma unroll
    for (int c = 0; c < 3; ++c) {
        if (c == 2 && !tile2ok) continue;
#pragma unroll
        for (int r = 0; r < 4; ++r) m = fmaxf(m, lv[c][r]);
    }
    m = fmaxf(m, __shfl_xor(m, 16));
    m = fmaxf(m, __shfl_xor(m, 32));
    float ssum = 0.f;
#pragma unroll
    for (int c = 0; c < 3; ++c) {
        if (c == 2 && !tile2ok) continue;
#pragma unroll
        for (int r = 0; r < 4; ++r) ssum += __expf(lv[c][r] - m);
    }
    ssum += __shfl_xor(ssum, 16);
    ssum += __shfl_xor(ssum, 32);
    float L = m + __logf(ssum);
    int node = br + wave * 16 + l16;
    if (node < N) {
#pragma unroll
        for (int c = 0; c < 3; ++c) {
            if (c == 2 && !tile2ok) continue;
            float4 o = make_float4(lv[c][0] - L, lv[c][1] - L, lv[c][2] - L, lv[c][3] - L);
            *((float4*)(out + (size_t)node * C + c * 16 + quad * 4)) = o;
        }
    }
}

// ---------------- launch ----------------

extern "C" void kernel_launch(void* const* d_in, const int* in_sizes, int n_in,
                              void* d_out, int out_size, void* d_ws, size_t ws_size,
                              hipStream_t stream) {
    const float* x    = (const float*)d_in[0];
    const int*   ei   = (const int*)d_in[1];
    const float* eps1 = (const float*)d_in[2];
    const float* w1   = (const float*)d_in[3];
    const float* b1   = (const float*)d_in[4];
    const float* w2   = (const float*)d_in[5];
    const float* b2   = (const float*)d_in[6];
    const float* eps2 = (const float*)d_in[7];
    const float* w3   = (const float*)d_in[8];
    const float* b3   = (const float*)d_in[9];
    const float* w4   = (const float*)d_in[10];
    const float* b4   = (const float*)d_in[11];
    float* out = (float*)d_out;

    int N = in_sizes[0] / F;       // 100000
    int E = in_sizes[1] / 2;       // 1600000
    const int* src = ei;
    const int* dst = ei + E;

    int NB = (N + BSIZE - 1) >> BSHIFT;   // 391 coarse buckets (<= 512)
    int BA = (E + CHUNK - 1) / CHUNK;

    // workspace layout
    __half* x_h  = (__half*)d_ws;                   // N*F
    __half* h0_h = x_h + (size_t)N * F;             // N*F
    __half* h_h  = h0_h + (size_t)N * F;            // N*F
    __half* w1t  = h_h + (size_t)N * F;             // 128*128
    __half* w2t  = w1t + 128 * 128;
    __half* w3t  = w2t + 128 * 128;
    __half* w4t  = w3t + 128 * 128;                 // 48*128
    unsigned* pairs   = (unsigned*)(w4t + 48 * 128); // E
    int* row_start    = (int*)(pairs + E);          // N+1
    int* src_sorted   = row_start + (N + 1);        // E
    int* coarse_count = src_sorted + E;             // 512
    int* coarse_start = coarse_count + 512;         // 513
    int* bucket_pos   = coarse_start + 513;         // 512

    // prep: fp16 conversions (+ zero coarse_count) + weight transposes
    int n4 = N * F / 4;
    conv_f16_kernel<<<(n4 + 255) / 256, 256, 0, stream>>>(x, x_h, n4, coarse_count, NB);
    prep_weights_kernel<<<4, 256, 0, stream>>>(w1, w2, w3, w4, w1t, w2t, w3t, w4t);

    // CSR build: coarse hist -> coarse scan -> bucket scatter -> per-bucket LDS sort
    coarse_hist_kernel<<<BA, 256, 0, stream>>>(dst, E, NB, coarse_count);
    coarse_scan_kernel<<<1, 512, 0, stream>>>(coarse_count, NB, E, coarse_start, bucket_pos,
                                              row_start, N);
    bucket_scatter_a_kernel<<<BA, 256, 0, stream>>>(src, dst, E, NB, bucket_pos, pairs);
    bucket_sort_kernel<<<NB, 256, 0, stream>>>(pairs, coarse_start, N, row_start, src_sorted);

    // layer 1
    agg_f16_kernel<<<(N + 3) / 4, 256, 0, stream>>>(x_h, row_start, src_sorted, eps1, h0_h, N);
    mlp1_mfma_kernel<<<(N + 63) / 64, 256, 0, stream>>>(h0_h, w1t, b1, w2t, b2, h_h, N);
    // layer 2
    agg_f16_kernel<<<(N + 3) / 4, 256, 0, stream>>>(h_h, row_start, src_sorted, eps2, h0_h, N);
    mlp2_mfma_kernel<<<(N + 63) / 64, 256, 0, stream>>>(h0_h, w3t, b3, w4t, b4, out, N);
}